// Round 7
// baseline (1004.241 us; speedup 1.0000x reference)
//
#include <hip/hip_runtime.h>
#include <cstdint>

#define B_SZ 2048
#define SEQ  16
#define DIM  1024
#define HID  512
#define DK   512
#define NH   4
#define DH   128
#define GATE 2048
#define EPSV 1e-5f

typedef __bf16 bf8_t __attribute__((ext_vector_type(8)));
typedef float  f4_t  __attribute__((ext_vector_type(4)));
typedef unsigned short u16x8 __attribute__((ext_vector_type(8)));
typedef unsigned short u16x4 __attribute__((ext_vector_type(4)));

__device__ __forceinline__ unsigned short f2bf(float f){
  __bf16 h = (__bf16)f;                       // RNE
  return __builtin_bit_cast(unsigned short, h);
}
__device__ __forceinline__ float bf2f(unsigned short u){
  return __builtin_bit_cast(float, ((unsigned int)u) << 16);
}
__device__ __forceinline__ float sigm(float x){ return 1.f/(1.f+__expf(-x)); }
__device__ __forceinline__ float tanh_f(float x){ return 1.f - 2.f/(__expf(2.f*x)+1.f); }

__device__ __forceinline__ void gload16(const void* g, void* l){
  __builtin_amdgcn_global_load_lds(
      (const __attribute__((address_space(1))) void*)g,
      (__attribute__((address_space(3))) void*)l, 16, 0, 0);
}

// ================= 256x256 8-phase double-buffered pipelined BT GEMM =================
// C(MxN) = A(MxK) @ B(NxK)^T, all bf16, granule-XOR swizzle (verified 0-conflict r3),
// chunked XCD swizzle. 8 waves (2Mx4N), per-wave 128x64 out. 2 K-tiles per iteration,
// 8 phases; phase = {ds_reads, 1 half-tile stage (2 gloads), barrier, 16 MFMA, barrier}.
// B-frags read once per K-tile (phase 0/4) and held in regs.
//
// LEDGER (steady state, per iteration i; tiles t0=2i->buf0, t1=2i+1->buf1):
//   stage plan: P0/P1: A(t1)h0/h1 -> buf1.A   [buf1.A freed at prev-iter P7 barrier]
//               P2/P3: B(t0+2)    -> buf0.B   [buf0.B freed at P0 barrier (B read only in P0)]
//               P4/P5: A(t0+2)    -> buf0.A   [buf0.A freed at P3 barrier]
//               P6/P7: B(t1+2)    -> buf1.B   [buf1.B freed at P4 barrier]
//   vmcnt(4) before P3 lead barrier: 12 outstanding {prevP6,prevP7,P0..P3}; 8 oldest
//     done = B(t1)+A(t1) -> valid for P4 reads (which occur after P3 trail barrier).
//   vmcnt(4) before P7 lead barrier: 12 outstanding {P2..P7}; 8 oldest done =
//     B(t0+2)+A(t0+2) -> valid for next-iter P0 reads.
//   Last iteration: stage tile indices CLAMPED (not skipped) so counts stay exact;
//   clamped stages write only dead buffer regions.
template<bool OUT_BF16, bool BIAS, bool RELU>
__global__ __launch_bounds__(512, 1) void gemm8p(
    const unsigned short* __restrict__ A,
    const unsigned short* __restrict__ Bw,
    const float* __restrict__ bias,
    void* __restrict__ Cp,
    int N, int K, int nwg)
{
  __shared__ __align__(16) unsigned short As[2][256*64];
  __shared__ __align__(16) unsigned short Bs[2][256*64];
  const int tid = threadIdx.x, lane = tid & 63, w = tid >> 6;
  const int bid = blockIdx.x;
  const int swz = (bid & 7)*(nwg >> 3) + (bid >> 3);   // nwg % 8 == 0 at all call sites
  const int nx  = N >> 8;
  const int lnx = 31 - __clz(nx);
  const int bm0 = (swz >> lnx) << 8;
  const int bn0 = (swz & (nx-1)) << 8;

  const int l8  = lane >> 3;                 // row within 8-row stage chunk
  const int gsw = (lane & 7) ^ l8;           // pre-swizzled source granule
  const int fr  = lane & 15, kg = lane >> 4;
  const int wm  = (w >> 2)*128, wn = (w & 3)*64;
  const int KT  = K >> 6;

  auto stA = [&](int buf, int kt, int h){    // stage half h of A K-tile kt (2 gloads)
    #pragma unroll
    for (int c=0;c<2;++c){
      const int rb = h*128 + c*64 + w*8;     // wave-uniform row base
      gload16(A + (size_t)(bm0 + rb + l8)*K + (size_t)kt*64 + gsw*8, &As[buf][rb*64]);
    }
  };
  auto stB = [&](int buf, int kt, int h){
    #pragma unroll
    for (int c=0;c<2;++c){
      const int rb = h*128 + c*64 + w*8;
      gload16(Bw + (size_t)(bn0 + rb + l8)*K + (size_t)kt*64 + gsw*8, &Bs[buf][rb*64]);
    }
  };
  auto rdA = [&](int buf, int m, int kk)->bf8_t{
    return *(const bf8_t*)&As[buf][(wm + m*16 + fr)*64 + (((kk*4+kg) ^ (fr&7))*8)];
  };
  auto rdB = [&](int buf, int n, int kk)->bf8_t{
    return *(const bf8_t*)&Bs[buf][(wn + n*16 + fr)*64 + (((kk*4+kg) ^ (fr&7))*8)];
  };

  f4_t acc[8][4];
  #pragma unroll
  for (int m=0;m<8;++m)
    #pragma unroll
    for (int n=0;n<4;++n) acc[m][n] = (f4_t)0.f;

  bf8_t bfr[4][2];

  auto mfma2 = [&](int m0, const bf8_t a00, const bf8_t a01,
                   const bf8_t a10, const bf8_t a11){
    __builtin_amdgcn_s_setprio(1);
    #pragma unroll
    for (int n=0;n<4;++n){
      acc[m0][n]   = __builtin_amdgcn_mfma_f32_16x16x32_bf16(a00, bfr[n][0], acc[m0][n],   0,0,0);
      acc[m0][n]   = __builtin_amdgcn_mfma_f32_16x16x32_bf16(a01, bfr[n][1], acc[m0][n],   0,0,0);
      acc[m0+1][n] = __builtin_amdgcn_mfma_f32_16x16x32_bf16(a10, bfr[n][0], acc[m0+1][n], 0,0,0);
      acc[m0+1][n] = __builtin_amdgcn_mfma_f32_16x16x32_bf16(a11, bfr[n][1], acc[m0+1][n], 0,0,0);
    }
    __builtin_amdgcn_s_setprio(0);
  };

  // phase with 12 ds_reads (B-all + A m0/m1) — P0 and P4
  auto phase12 = [&](int buf, auto&& stg){
    #pragma unroll
    for (int n=0;n<4;++n){ bfr[n][0]=rdB(buf,n,0); bfr[n][1]=rdB(buf,n,1); }
    const bf8_t a00=rdA(buf,0,0), a01=rdA(buf,0,1), a10=rdA(buf,1,0), a11=rdA(buf,1,1);
    stg();
    asm volatile("s_barrier" ::: "memory");
    mfma2(0, a00,a01,a10,a11);
    asm volatile("s_barrier" ::: "memory");
  };
  // phase with 4 ds_reads (A m0/m0+1) — P1..P3, P5..P7; vm: counted vmcnt before lead barrier
  auto phase4 = [&](int buf, int m0, auto&& stg, bool vm){
    const bf8_t a00=rdA(buf,m0,0), a01=rdA(buf,m0,1), a10=rdA(buf,m0+1,0), a11=rdA(buf,m0+1,1);
    stg();
    if (vm){
      __builtin_amdgcn_sched_barrier(0);
      asm volatile("s_waitcnt vmcnt(4)" ::: "memory");
    }
    asm volatile("s_barrier" ::: "memory");
    mfma2(m0, a00,a01,a10,a11);
    asm volatile("s_barrier" ::: "memory");
  };

  // prologue: A(0), B(0) full; B(1) full; wait A(0)+B(0) (8 oldest of 12)
  stA(0,0,0); stA(0,0,1); stB(0,0,0); stB(0,0,1);
  stB(1,1,0); stB(1,1,1);
  __builtin_amdgcn_sched_barrier(0);
  asm volatile("s_waitcnt vmcnt(4)" ::: "memory");
  asm volatile("s_barrier" ::: "memory");

  const int NIT = KT >> 1;
  for (int it=0; it<NIT; ++it){
    const int t0 = 2*it, t1 = t0+1;
    const int tN  = (t0+2 < KT) ? t0+2 : KT-1;   // clamped (dead-region write on last iter)
    const int tB3 = (t1+2 < KT) ? t1+2 : KT-1;

    phase12(0,      [&]{ stA(1,t1,0);  });            // P0
    phase4 (0, 2,   [&]{ stA(1,t1,1);  }, false);     // P1
    phase4 (0, 4,   [&]{ stB(0,tN,0);  }, false);     // P2
    phase4 (0, 6,   [&]{ stB(0,tN,1);  }, true);      // P3  (vmcnt(4): A(t1),B(t1) ready)
    phase12(1,      [&]{ stA(0,tN,0);  });            // P4
    phase4 (1, 2,   [&]{ stA(0,tN,1);  }, false);     // P5
    phase4 (1, 4,   [&]{ stB(1,tB3,0); }, false);     // P6
    phase4 (1, 6,   [&]{ stB(1,tB3,1); }, true);      // P7  (vmcnt(4): tile t0+2 ready)
  }

  #pragma unroll
  for (int n=0;n<4;++n){
    const int col = bn0 + wn + n*16 + fr;
    float bv = 0.f;
    if constexpr (BIAS) bv = bias[col];
    #pragma unroll
    for (int m=0;m<8;++m){
      #pragma unroll
      for (int j=0;j<4;++j){
        const int row = bm0 + wm + m*16 + kg*4 + j;
        float v = acc[m][n][j] + bv;
        if constexpr (RELU) v = fmaxf(v, 0.f);
        if constexpr (OUT_BF16) ((unsigned short*)Cp)[(size_t)row*N + col] = f2bf(v);
        else                    ((float*)Cp)[(size_t)row*N + col] = v;
      }
    }
  }
}

// ------------- bf16 BT GEMM 64x64 (high-occupancy, for the small recurrent GEMMs; r3-proven) -------------
template<bool OUT_BF16, bool BIAS>
__global__ __launch_bounds__(256) void gemm64(
    const unsigned short* __restrict__ A,
    const unsigned short* __restrict__ Bw,
    const float* __restrict__ bias,
    void* __restrict__ Cp,
    int N, int K, int nwg)
{
  __shared__ __align__(16) unsigned short As[64*64];
  __shared__ __align__(16) unsigned short Bs[64*64];
  const int tid = threadIdx.x, lane = tid & 63, wave = tid >> 6;
  const int bid = blockIdx.x;
  const int swz = (bid & 7)*(nwg >> 3) + (bid >> 3);
  const int nx  = N >> 6;
  const int lnx = 31 - __clz(nx);
  const int bm0 = (swz >> lnx) << 6;
  const int bn0 = (swz & (nx-1)) << 6;

  const int r8  = lane >> 3;
  const int gsw = ((lane & 7) ^ r8) * 8;
  const unsigned short* Ab = A  + (size_t)(bm0 + wave*16 + r8)*K + gsw;
  const unsigned short* Bb = Bw + (size_t)(bn0 + wave*16 + r8)*K + gsw;
  unsigned short* la = As + wave*1024;
  unsigned short* lb = Bs + wave*1024;

  f4_t acc[2][2];
  #pragma unroll
  for (int m=0;m<2;++m)
    #pragma unroll
    for (int n=0;n<2;++n) acc[m][n] = (f4_t)0.f;

  const int KT = K >> 6;
  const int fr = lane & 15, kg = lane >> 4;
  const int wm = (wave & 1)*32, wn = (wave >> 1)*32;

  for (int kt = 0; kt < KT; ++kt){
    if (kt) __syncthreads();
    const size_t ko = (size_t)kt*64;
    #pragma unroll
    for (int q = 0; q < 2; ++q){
      gload16(Ab + ko + (size_t)q*8*K, la + q*512);
      gload16(Bb + ko + (size_t)q*8*K, lb + q*512);
    }
    __syncthreads();
    #pragma unroll
    for (int kk = 0; kk < 2; ++kk){
      bf8_t af[2], bf_[2];
      #pragma unroll
      for (int m=0;m<2;++m){
        const int r = wm+m*16+fr;
        af[m]  = *(const bf8_t*)&As[r*64 + (((kk*4+kg) ^ (r&7))*8)];
      }
      #pragma unroll
      for (int n=0;n<2;++n){
        const int r = wn+n*16+fr;
        bf_[n] = *(const bf8_t*)&Bs[r*64 + (((kk*4+kg) ^ (r&7))*8)];
      }
      #pragma unroll
      for (int m=0;m<2;++m)
        #pragma unroll
        for (int n=0;n<2;++n)
          acc[m][n] = __builtin_amdgcn_mfma_f32_16x16x32_bf16(af[m], bf_[n], acc[m][n], 0,0,0);
    }
  }

  #pragma unroll
  for (int n=0;n<2;++n){
    const int col = bn0 + wn + n*16 + fr;
    float bv = 0.f;
    if constexpr (BIAS) bv = bias[col];
    #pragma unroll
    for (int m=0;m<2;++m){
      #pragma unroll
      for (int j=0;j<4;++j){
        const int row = bm0 + wm + m*16 + kg*4 + j;
        float v = acc[m][n][j] + bv;
        if constexpr (OUT_BF16) ((unsigned short*)Cp)[(size_t)row*N + col] = f2bf(v);
        else                    ((float*)Cp)[(size_t)row*N + col] = v;
      }
    }
  }
}

// ---------------- fused LN + LSTM elementwise step (one WG per batch row; r3-proven) ----------------
__global__ __launch_bounds__(256) void lstm_step(
  const unsigned short* __restrict__ X, const unsigned short* __restrict__ Gh,
  const float* __restrict__ c_src, float* __restrict__ c_dst,
  const float* __restrict__ g_ih, const float* __restrict__ b_ih,
  const float* __restrict__ g_hh, const float* __restrict__ b_hh,
  const float* __restrict__ g_c,  const float* __restrict__ b_c,
  unsigned short* __restrict__ h_out, unsigned short* __restrict__ lstm_out,
  int t)
{
  const int b = blockIdx.x, tid = threadIdx.x;
  __shared__ float xs[GATE];
  __shared__ float gs[GATE];
  __shared__ float red[32];
  const unsigned short* xrow = X  + ((size_t)b*SEQ + t)*GATE;
  const unsigned short* grow = Gh + (size_t)b*GATE;
  u16x8 xv = *(const u16x8*)&xrow[tid*8];
  u16x8 gv = *(const u16x8*)&grow[tid*8];
  float sx=0,sx2=0,sg=0,sg2=0;
  #pragma unroll
  for (int j=0;j<8;++j){
    float x = bf2f(xv[j]), g = bf2f(gv[j]);
    xs[tid*8+j]=x; gs[tid*8+j]=g;
    sx += x; sx2 += x*x; sg += g; sg2 += g*g;
  }
  #pragma unroll
  for (int m=32;m;m>>=1){
    sx += __shfl_xor(sx,m); sx2 += __shfl_xor(sx2,m);
    sg += __shfl_xor(sg,m); sg2 += __shfl_xor(sg2,m);
  }
  const int w = tid>>6;
  if ((tid&63)==0){ red[w]=sx; red[4+w]=sx2; red[8+w]=sg; red[12+w]=sg2; }
  __syncthreads();
  sx  = red[0]+red[1]+red[2]+red[3];
  sx2 = red[4]+red[5]+red[6]+red[7];
  sg  = red[8]+red[9]+red[10]+red[11];
  sg2 = red[12]+red[13]+red[14]+red[15];
  const float mX = sx*(1.f/GATE), mH = sg*(1.f/GATE);
  const float rX = rsqrtf(sx2*(1.f/GATE)-mX*mX+EPSV);
  const float rH = rsqrtf(sg2*(1.f/GATE)-mH*mH+EPSV);

  float cN[2], xo[2]; float sc=0, sc2=0;
  #pragma unroll
  for (int rep=0;rep<2;++rep){
    const int n = tid + rep*256;
    const int ni=n, nf=n+HID, ng=n+2*HID, no=n+3*HID;
    float gi = (xs[ni]-mX)*rX*g_ih[ni]+b_ih[ni] + (gs[ni]-mH)*rH*g_hh[ni]+b_hh[ni];
    float gf = (xs[nf]-mX)*rX*g_ih[nf]+b_ih[nf] + (gs[nf]-mH)*rH*g_hh[nf]+b_hh[nf];
    float gg = (xs[ng]-mX)*rX*g_ih[ng]+b_ih[ng] + (gs[ng]-mH)*rH*g_hh[ng]+b_hh[ng];
    float go = (xs[no]-mX)*rX*g_ih[no]+b_ih[no] + (gs[no]-mH)*rH*g_hh[no]+b_hh[no];
    float co = c_src[(size_t)b*HID + n];
    float cn = sigm(gf)*co + sigm(gi)*tanh_f(gg);
    cN[rep]=cn; xo[rep]=go;
    sc += cn; sc2 += cn*cn;
  }
  #pragma unroll
  for (int m=32;m;m>>=1){ sc += __shfl_xor(sc,m); sc2 += __shfl_xor(sc2,m); }
  if ((tid&63)==0){ red[16+w]=sc; red[20+w]=sc2; }
  __syncthreads();
  sc  = red[16]+red[17]+red[18]+red[19];
  sc2 = red[20]+red[21]+red[22]+red[23];
  const float mC = sc*(1.f/HID);
  const float rC = rsqrtf(sc2*(1.f/HID)-mC*mC+EPSV);
  #pragma unroll
  for (int rep=0;rep<2;++rep){
    const int n = tid + rep*256;
    float hN = sigm(xo[rep])*tanh_f((cN[rep]-mC)*rC*g_c[n]+b_c[n]);
    c_dst[(size_t)b*HID+n] = cN[rep];
    unsigned short hbv = f2bf(hN);
    h_out[(size_t)b*HID+n] = hbv;
    lstm_out[((size_t)b*SEQ+t)*HID+n] = hbv;
  }
}

// ---------------- fused attention: scores -> softmax -> pooled -> scalar out ----------------
__global__ __launch_bounds__(256) void attn_out_k(
  const float* __restrict__ q, const unsigned short* __restrict__ Km,
  const unsigned short* __restrict__ lo_all,
  const float* __restrict__ u, const float* __restrict__ Cc,
  float* __restrict__ out)
{
  const int b = blockIdx.x, tid = threadIdx.x;
  __shared__ float qs[DK];
  __shared__ float sc[NH][SEQ];
  __shared__ float at[NH][SEQ];
  __shared__ float red[4];
  for (int i=tid; i<DK; i+=256) qs[i] = q[(size_t)b*DK + i];
  __syncthreads();
  {
    const int p = tid>>2, sub = tid&3, h = p>>4, s = p&15;
    const unsigned short* krow = Km + ((size_t)b*SEQ + s)*DK + h*DH + sub*32;
    const float* qh = &qs[h*DH + sub*32];
    float part = 0.f;
    #pragma unroll
    for (int c8=0;c8<4;++c8){
      u16x8 kv = *(const u16x8*)(krow + c8*8);
      #pragma unroll
      for (int j=0;j<8;++j) part += qh[c8*8+j]*bf2f(kv[j]);
    }
    part += __shfl_xor(part,1); part += __shfl_xor(part,2);
    if (sub==0) sc[h][s] = part * 0.08838834764831845f;
  }
  __syncthreads();
  if (tid < 64){
    const int h = tid>>4;
    float v = sc[h][tid&15], mx = v;
    #pragma unroll
    for (int m=1;m<16;m<<=1) mx = fmaxf(mx, __shfl_xor(mx,m));
    float e = __expf(v-mx), se = e;
    #pragma unroll
    for (int m=1;m<16;m<<=1) se += __shfl_xor(se,m);
    at[h][tid&15] = e/se;
  }
  __syncthreads();
  float accum = 0.f;
  #pragma unroll
  for (int it=0; it<4; ++it){
    const int idx = it*256 + tid;
    const int h = idx>>8, d0 = (idx&255)*2;
    const unsigned short* lo = lo_all + (size_t)b*SEQ*HID + d0;
    float p0=0.f, p1=0.f;
    #pragma unroll
    for (int s=0;s<16;++s){
      unsigned int pr = *(const unsigned int*)(lo + s*HID);
      float a = at[h][s];
      p0 += a*bf2f((unsigned short)(pr&0xffffu));
      p1 += a*bf2f((unsigned short)(pr>>16));
    }
    accum += u[h*HID+d0]*p0 + u[h*HID+d0+1]*p1;
  }
  #pragma unroll
  for (int m=32;m;m>>=1) accum += __shfl_xor(accum,m);
  if ((tid&63)==0) red[tid>>6] = accum;
  __syncthreads();
  if (tid==0) out[1+b] = red[0]+red[1]+red[2]+red[3] + Cc[0];
}

__global__ __launch_bounds__(256) void loss_k(const float* __restrict__ label, float* __restrict__ out){
  const int tid = threadIdx.x;
  __shared__ float red[4];
  float s = 0.f;
  for (int b=tid; b<B_SZ; b+=256){
    float d = out[1+b] - label[(size_t)b*SEQ + (SEQ-1)];
    s += d*d;
  }
  #pragma unroll
  for (int m=32;m;m>>=1) s += __shfl_xor(s,m);
  if ((tid&63)==0) red[tid>>6]=s;
  __syncthreads();
  if (tid==0) out[0] = (red[0]+red[1]+red[2]+red[3]) * (1.f/B_SZ);
}

__global__ __launch_bounds__(256) void cvt_bf16_k(const float* __restrict__ in, unsigned short* __restrict__ o, int n){
  int i = (blockIdx.x*256 + threadIdx.x)*4;
  if (i < n){
    f4_t v = *(const f4_t*)&in[i];
    u16x4 w;
    #pragma unroll
    for (int j=0;j<4;++j) w[j] = f2bf(v[j]);
    *(u16x4*)&o[i] = w;
  }
}

// concat+convert the 4 modality tensors into modsB[32768][4096] bf16
__global__ __launch_bounds__(256) void cvt4_k(
  const float* __restrict__ v0, const float* __restrict__ v1,
  const float* __restrict__ v2, const float* __restrict__ v3,
  unsigned short* __restrict__ dst)
{
  const int idx = blockIdx.x*256 + threadIdx.x;   // 8 elements each
  const int src = blockIdx.y;
  const float* s = src==0?v0 : src==1?v1 : src==2?v2 : v3;
  const size_t e0 = (size_t)idx*8;
  const int row = (int)(e0 >> 10);
  const int col = (int)(e0 & 1023);
  f4_t a = *(const f4_t*)&s[e0];
  f4_t b = *(const f4_t*)&s[e0+4];
  u16x8 w;
  #pragma unroll
  for (int j=0;j<4;++j){ w[j]=f2bf(a[j]); w[4+j]=f2bf(b[j]); }
  *(u16x8*)&dst[(size_t)row*4096 + src*1024 + col] = w;
}

// -------- fold wout/out_W/wv into u[h,d] and scalar C (exact: sum(attn)==1) --------
__global__ __launch_bounds__(256) void fold_we_k(
  const float* __restrict__ wout_W, const float* __restrict__ out_W, float* __restrict__ we)
{
  const int j = blockIdx.x*256 + threadIdx.x;
  float s=0.f;
  for (int m=0;m<512;++m) s += out_W[m]*wout_W[(size_t)m*2048+j];
  we[j]=s;
}
__global__ __launch_bounds__(256) void fold_u_k(
  const float* __restrict__ we, const float* __restrict__ wv_W, float* __restrict__ u)
{
  const int o = blockIdx.x*256 + threadIdx.x;
  const int h = o>>9, d = o&511;
  const float* wv = wv_W + (size_t)h*262144 + d;
  const float* wp = we + h*512;
  float s=0.f;
  for (int k=0;k<512;++k) s += wp[k]*wv[(size_t)k*512];
  u[o]=s;
}
__global__ __launch_bounds__(256) void fold_c_k(
  const float* __restrict__ we, const float* __restrict__ wv_b,
  const float* __restrict__ out_W, const float* __restrict__ wout_b,
  const float* __restrict__ out_b, float* __restrict__ Cc)
{
  const int tid = threadIdx.x;
  __shared__ float red[4];
  float s=0.f;
  for (int j=tid;j<2048;j+=256) s += we[j]*wv_b[j];
  for (int m=tid;m<512;m+=256)  s += out_W[m]*wout_b[m];
  #pragma unroll
  for (int m=32;m;m>>=1) s += __shfl_xor(s,m);
  if ((tid&63)==0) red[tid>>6]=s;
  __syncthreads();
  if (tid==0) Cc[0] = red[0]+red[1]+red[2]+red[3] + out_b[0];
}

extern "C" void kernel_launch(void* const* d_in, const int* in_sizes, int n_in,
                              void* d_out, int out_size, void* d_ws, size_t ws_size,
                              hipStream_t stream)
{
  const float* visual = (const float*)d_in[0];
  const float* text   = (const float*)d_in[1];
  const float* user_  = (const float*)d_in[2];
  const float* cat_   = (const float*)d_in[3];
  const float* label  = (const float*)d_in[4];
  const float* h0     = (const float*)d_in[5];
  const float* c0     = (const float*)d_in[6];
  const float* fus_W  = (const float*)d_in[7];
  const float* fus_b  = (const float*)d_in[8];
  const float* W_ih   = (const float*)d_in[9];
  const float* W_hh   = (const float*)d_in[10];
  const float* g_ih   = (const float*)d_in[11];
  const float* b_ih   = (const float*)d_in[12];
  const float* g_hh   = (const float*)d_in[13];
  const float* b_hh   = (const float*)d_in[14];
  const float* g_c    = (const float*)d_in[15];
  const float* b_c    = (const float*)d_in[16];
  const float* wq_W   = (const float*)d_in[17];
  const float* wq_b   = (const float*)d_in[18];
  const float* wk_W   = (const float*)d_in[19];
  const float* wk_b   = (const float*)d_in[20];
  const float* wv_W   = (const float*)d_in[21];
  const float* wv_b   = (const float*)d_in[22];
  const float* wout_W = (const float*)d_in[23];
  const float* wout_b = (const float*)d_in[24];
  const float* out_W  = (const float*)d_in[25];
  const float* out_b  = (const float*)d_in[26];
  (void)in_sizes; (void)n_in; (void)out_size; (void)ws_size;

  char* base = (char*)d_ws; size_t off = 0;
  auto alloc = [&](size_t n)->void*{ void* p = base+off; off += n; off = (off+255)&~(size_t)255; return p; };
  unsigned short* modsB = (unsigned short*)alloc((size_t)32768*4096*2);  // 256 MB; reused as X
  unsigned short* X     = modsB;                                         // alias (modsB dead after GEMM1)
  unsigned short* vt    = (unsigned short*)alloc((size_t)32768*1024*2);
  unsigned short* lo    = (unsigned short*)alloc((size_t)32768*512*2);
  unsigned short* Km    = (unsigned short*)alloc((size_t)32768*512*2);
  unsigned short* Gh    = (unsigned short*)alloc((size_t)2048*2048*2);
  float*          cws   = (float*)         alloc((size_t)2048*512*4);
  unsigned short* hb    = (unsigned short*)alloc((size_t)2048*512*2);
  float*          qb    = (float*)         alloc((size_t)2048*512*4);
  unsigned short* fusWb = (unsigned short*)alloc((size_t)1024*4096*2);
  unsigned short* Wihb  = (unsigned short*)alloc((size_t)2048*1024*2);
  unsigned short* Whhb  = (unsigned short*)alloc((size_t)2048*512*2);
  unsigned short* wqb   = (unsigned short*)alloc((size_t)512*512*2);
  unsigned short* wkb   = (unsigned short*)alloc((size_t)512*512*2);
  float*          we_ws = (float*)         alloc(2048*4);
  float*          u_ws  = (float*)         alloc(2048*4);
  float*          C_ws  = (float*)         alloc(256);

  // conversions + folds
  cvt4_k<<<dim3(16384,4), dim3(256), 0, stream>>>(visual, text, user_, cat_, modsB);
  cvt_bf16_k<<<dim3(4096), dim3(256), 0, stream>>>(fus_W, fusWb, 1024*4096);
  cvt_bf16_k<<<dim3(2048), dim3(256), 0, stream>>>(W_ih,  Wihb,  2048*1024);
  cvt_bf16_k<<<dim3(1024), dim3(256), 0, stream>>>(W_hh,  Whhb,  2048*512);
  cvt_bf16_k<<<dim3(256),  dim3(256), 0, stream>>>(wq_W,  wqb,   512*512);
  cvt_bf16_k<<<dim3(256),  dim3(256), 0, stream>>>(wk_W,  wkb,   512*512);
  cvt_bf16_k<<<dim3(1024), dim3(256), 0, stream>>>(h0,    hb,    2048*512);
  fold_we_k<<<dim3(8), dim3(256), 0, stream>>>(wout_W, out_W, we_ws);
  fold_u_k <<<dim3(8), dim3(256), 0, stream>>>(we_ws, wv_W, u_ws);
  fold_c_k <<<dim3(1), dim3(256), 0, stream>>>(we_ws, wv_b, out_W, wout_b, out_b, C_ws);

  // GEMM1: vt = relu(modsB @ fus_W^T + fus_b)   M=32768 N=1024 K=4096  (512 WGs, 256^2 tiles)
  gemm8p<true,true,true><<<dim3(512), dim3(512), 0, stream>>>(
      modsB, fusWb, fus_b, vt, 1024, 4096, 512);
  // GEMM2: X = vt @ W_ih^T  (bf16 out; LN renormalizes)  M=32768 N=2048 K=1024  (1024 WGs)
  gemm8p<true,false,false><<<dim3(1024), dim3(512), 0, stream>>>(
      vt, Wihb, nullptr, X, 2048, 1024, 1024);

  // recurrence (r3-proven: 64x64 tiles -> 1024 WGs, 4/CU)
  for (int t=0; t<SEQ; ++t){
    gemm64<true,false><<<dim3(1024), dim3(256), 0, stream>>>(
        hb, Whhb, nullptr, Gh, 2048, 512, 1024);
    lstm_step<<<dim3(2048), dim3(256), 0, stream>>>(
        X, Gh, (t==0 ? c0 : cws), cws, g_ih, b_ih, g_hh, b_hh, g_c, b_c, hb, lo, t);
  }

  // q = hn @ wq_W^T + wq_b   (fp32 out)  M=2048 N=512 K=512
  gemm64<false,true><<<dim3(256), dim3(256), 0, stream>>>(
      hb, wqb, wq_b, qb, 512, 512, 256);
  // Kmat = lstm_out @ wk_W^T + wk_b  (bf16 out)  M=32768 N=512 K=512  (256 WGs)
  gemm8p<true,true,false><<<dim3(256), dim3(512), 0, stream>>>(
      lo, wkb, wk_b, Km, 512, 512, 256);

  attn_out_k<<<dim3(2048), dim3(256), 0, stream>>>(qb, Km, lo, u_ws, C_ws, (float*)d_out);
  loss_k<<<dim3(1), dim3(256), 0, stream>>>(label, (float*)d_out);
}

// Round 8
// 978.316 us; speedup vs baseline: 1.0265x; 1.0265x over previous
//
#include <hip/hip_runtime.h>
#include <cstdint>

#define B_SZ 2048
#define SEQ  16
#define DIM  1024
#define HID  512
#define DK   512
#define NH   4
#define DH   128
#define GATE 2048
#define EPSV 1e-5f

typedef __bf16 bf8_t __attribute__((ext_vector_type(8)));
typedef float  f4_t  __attribute__((ext_vector_type(4)));
typedef unsigned short u16x8 __attribute__((ext_vector_type(8)));
typedef unsigned short u16x4 __attribute__((ext_vector_type(4)));

__device__ __forceinline__ unsigned short f2bf(float f){
  __bf16 h = (__bf16)f;                       // RNE
  return __builtin_bit_cast(unsigned short, h);
}
__device__ __forceinline__ float bf2f(unsigned short u){
  return __builtin_bit_cast(float, ((unsigned int)u) << 16);
}
__device__ __forceinline__ float sigm(float x){ return 1.f/(1.f+__expf(-x)); }
__device__ __forceinline__ float tanh_f(float x){ return 1.f - 2.f/(__expf(2.f*x)+1.f); }

__device__ __forceinline__ void gload16(const void* g, void* l){
  __builtin_amdgcn_global_load_lds(
      (const __attribute__((address_space(1))) void*)g,
      (__attribute__((address_space(3))) void*)l, 16, 0, 0);
}

// ================= 256x256 8-phase pipelined BT GEMM, bf16 A (r7-proven 968 TF) =================
template<bool OUT_BF16, bool BIAS, bool RELU>
__global__ __launch_bounds__(512, 1) void gemm8p(
    const unsigned short* __restrict__ A,
    const unsigned short* __restrict__ Bw,
    const float* __restrict__ bias,
    void* __restrict__ Cp,
    int N, int K, int nwg)
{
  __shared__ __align__(16) unsigned short As[2][256*64];
  __shared__ __align__(16) unsigned short Bs[2][256*64];
  const int tid = threadIdx.x, lane = tid & 63, w = tid >> 6;
  const int bid = blockIdx.x;
  const int swz = (bid & 7)*(nwg >> 3) + (bid >> 3);   // nwg % 8 == 0 at all call sites
  const int nx  = N >> 8;
  const int lnx = 31 - __clz(nx);
  const int bm0 = (swz >> lnx) << 8;
  const int bn0 = (swz & (nx-1)) << 8;

  const int l8  = lane >> 3;
  const int gsw = (lane & 7) ^ l8;
  const int fr  = lane & 15, kg = lane >> 4;
  const int wm  = (w >> 2)*128, wn = (w & 3)*64;
  const int KT  = K >> 6;

  auto stA = [&](int buf, int kt, int h){
    #pragma unroll
    for (int c=0;c<2;++c){
      const int rb = h*128 + c*64 + w*8;
      gload16(A + (size_t)(bm0 + rb + l8)*K + (size_t)kt*64 + gsw*8, &As[buf][rb*64]);
    }
  };
  auto stB = [&](int buf, int kt, int h){
    #pragma unroll
    for (int c=0;c<2;++c){
      const int rb = h*128 + c*64 + w*8;
      gload16(Bw + (size_t)(bn0 + rb + l8)*K + (size_t)kt*64 + gsw*8, &Bs[buf][rb*64]);
    }
  };
  auto rdA = [&](int buf, int m, int kk)->bf8_t{
    return *(const bf8_t*)&As[buf][(wm + m*16 + fr)*64 + (((kk*4+kg) ^ (fr&7))*8)];
  };
  auto rdB = [&](int buf, int n, int kk)->bf8_t{
    return *(const bf8_t*)&Bs[buf][(wn + n*16 + fr)*64 + (((kk*4+kg) ^ (fr&7))*8)];
  };

  f4_t acc[8][4];
  #pragma unroll
  for (int m=0;m<8;++m)
    #pragma unroll
    for (int n=0;n<4;++n) acc[m][n] = (f4_t)0.f;

  bf8_t bfr[4][2];

  auto mfma2 = [&](int m0, const bf8_t a00, const bf8_t a01,
                   const bf8_t a10, const bf8_t a11){
    __builtin_amdgcn_s_setprio(1);
    #pragma unroll
    for (int n=0;n<4;++n){
      acc[m0][n]   = __builtin_amdgcn_mfma_f32_16x16x32_bf16(a00, bfr[n][0], acc[m0][n],   0,0,0);
      acc[m0][n]   = __builtin_amdgcn_mfma_f32_16x16x32_bf16(a01, bfr[n][1], acc[m0][n],   0,0,0);
      acc[m0+1][n] = __builtin_amdgcn_mfma_f32_16x16x32_bf16(a10, bfr[n][0], acc[m0+1][n], 0,0,0);
      acc[m0+1][n] = __builtin_amdgcn_mfma_f32_16x16x32_bf16(a11, bfr[n][1], acc[m0+1][n], 0,0,0);
    }
    __builtin_amdgcn_s_setprio(0);
  };

  auto phase12 = [&](int buf, auto&& stg){
    #pragma unroll
    for (int n=0;n<4;++n){ bfr[n][0]=rdB(buf,n,0); bfr[n][1]=rdB(buf,n,1); }
    const bf8_t a00=rdA(buf,0,0), a01=rdA(buf,0,1), a10=rdA(buf,1,0), a11=rdA(buf,1,1);
    stg();
    asm volatile("s_barrier" ::: "memory");
    mfma2(0, a00,a01,a10,a11);
    asm volatile("s_barrier" ::: "memory");
  };
  auto phase4 = [&](int buf, int m0, auto&& stg, bool vm){
    const bf8_t a00=rdA(buf,m0,0), a01=rdA(buf,m0,1), a10=rdA(buf,m0+1,0), a11=rdA(buf,m0+1,1);
    stg();
    if (vm){
      __builtin_amdgcn_sched_barrier(0);
      asm volatile("s_waitcnt vmcnt(4)" ::: "memory");
    }
    asm volatile("s_barrier" ::: "memory");
    mfma2(m0, a00,a01,a10,a11);
    asm volatile("s_barrier" ::: "memory");
  };

  stA(0,0,0); stA(0,0,1); stB(0,0,0); stB(0,0,1);
  stB(1,1,0); stB(1,1,1);
  __builtin_amdgcn_sched_barrier(0);
  asm volatile("s_waitcnt vmcnt(4)" ::: "memory");
  asm volatile("s_barrier" ::: "memory");

  const int NIT = KT >> 1;
  for (int it=0; it<NIT; ++it){
    const int t0 = 2*it, t1 = t0+1;
    const int tN  = (t0+2 < KT) ? t0+2 : KT-1;
    const int tB3 = (t1+2 < KT) ? t1+2 : KT-1;

    phase12(0,      [&]{ stA(1,t1,0);  });
    phase4 (0, 2,   [&]{ stA(1,t1,1);  }, false);
    phase4 (0, 4,   [&]{ stB(0,tN,0);  }, false);
    phase4 (0, 6,   [&]{ stB(0,tN,1);  }, true);
    phase12(1,      [&]{ stA(0,tN,0);  });
    phase4 (1, 2,   [&]{ stA(0,tN,1);  }, false);
    phase4 (1, 4,   [&]{ stB(1,tB3,0); }, false);
    phase4 (1, 6,   [&]{ stB(1,tB3,1); }, true);
  }

  #pragma unroll
  for (int n=0;n<4;++n){
    const int col = bn0 + wn + n*16 + fr;
    float bv = 0.f;
    if constexpr (BIAS) bv = bias[col];
    #pragma unroll
    for (int m=0;m<8;++m){
      #pragma unroll
      for (int j=0;j<4;++j){
        const int row = bm0 + wm + m*16 + kg*4 + j;
        float v = acc[m][n][j] + bv;
        if constexpr (RELU) v = fmaxf(v, 0.f);
        if constexpr (OUT_BF16) ((unsigned short*)Cp)[(size_t)row*N + col] = f2bf(v);
        else                    ((float*)Cp)[(size_t)row*N + col] = v;
      }
    }
  }
}

// ===== 256x256 8-phase GEMM with FUSED fp32->bf16 A conversion (GEMM1; kills cvt4) =====
// A from 4 fp32 sources (concat K=4096). A staged T14-style: reg-load 128 rows (16 f32/thr)
// at phase p, cvt+swizzled ds_write at p+1 (one rg[4] set reused 4x/iter). B via gload_lds.
// LEDGER: wrA at P1/P2 (resp P5/P6) auto-waits its reg-loads; in-order vmcnt counting means
// those waits force ALL older B-gloads complete -> B(t1) resident by P2 (< P3-trail barrier),
// B(t0+2) forced by P5/P6 auto-waits (< P7-trail). buf1.A writes done P2 + lgkmcnt(0) at P3
// before trail barrier; buf0.A writes done P6 + lgkmcnt(0) at P7. Clamped tail keeps counts.
__global__ __launch_bounds__(512, 1) void gemm8pf(
    const float* __restrict__ A0, const float* __restrict__ A1,
    const float* __restrict__ A2, const float* __restrict__ A3,
    const unsigned short* __restrict__ Bw,
    const float* __restrict__ bias,
    unsigned short* __restrict__ Cp,
    int N, int K, int nwg)
{
  __shared__ __align__(16) unsigned short As[2][256*64];
  __shared__ __align__(16) unsigned short Bs[2][256*64];
  const int tid = threadIdx.x, lane = tid & 63, w = tid >> 6;
  const int bid = blockIdx.x;
  const int swz = (bid & 7)*(nwg >> 3) + (bid >> 3);
  const int nx  = N >> 8;
  const int lnx = 31 - __clz(nx);
  const int bm0 = (swz >> lnx) << 8;
  const int bn0 = (swz & (nx-1)) << 8;

  const int l8  = lane >> 3;
  const int gsw = (lane & 7) ^ l8;
  const int fr  = lane & 15, kg = lane >> 4;
  const int wm  = (w >> 2)*128, wn = (w & 3)*64;
  const int KT  = K >> 6;

  auto stB = [&](int buf, int kt, int h){
    #pragma unroll
    for (int c=0;c<2;++c){
      const int rb = h*128 + c*64 + w*8;
      gload16(Bw + (size_t)(bn0 + rb + l8)*K + (size_t)kt*64 + gsw*8, &Bs[buf][rb*64]);
    }
  };

  // A staging: thread -> row tid>>2 within 128-row half, 16 consecutive f32 at col (tid&3)*16
  f4_t rg[4];
  auto ldA = [&](int kt, int h){
    const int kb = kt*64, si = kb >> 10, kc = kb & 1023;
    const float* Asel = si==0?A0 : si==1?A1 : si==2?A2 : A3;
    const float* p = Asel + (size_t)(bm0 + h*128 + (tid>>2))*1024 + kc + (tid&3)*16;
    rg[0] = *(const f4_t*)p;     rg[1] = *(const f4_t*)(p+4);
    rg[2] = *(const f4_t*)(p+8); rg[3] = *(const f4_t*)(p+12);
  };
  auto wrA = [&](int buf, int h){
    const int row = h*128 + (tid>>2);
    const int s = row & 7, g0 = (tid&3)*2;
    u16x8 w0, w1;
    #pragma unroll
    for (int j=0;j<4;++j){
      w0[j]=f2bf(rg[0][j]); w0[4+j]=f2bf(rg[1][j]);
      w1[j]=f2bf(rg[2][j]); w1[4+j]=f2bf(rg[3][j]);
    }
    *(u16x8*)&As[buf][row*64 + ((g0^s)*8)]     = w0;
    *(u16x8*)&As[buf][row*64 + (((g0+1)^s)*8)] = w1;
  };

  auto rdA = [&](int buf, int m, int kk)->bf8_t{
    return *(const bf8_t*)&As[buf][(wm + m*16 + fr)*64 + (((kk*4+kg) ^ (fr&7))*8)];
  };
  auto rdB = [&](int buf, int n, int kk)->bf8_t{
    return *(const bf8_t*)&Bs[buf][(wn + n*16 + fr)*64 + (((kk*4+kg) ^ (fr&7))*8)];
  };

  f4_t acc[8][4];
  #pragma unroll
  for (int m=0;m<8;++m)
    #pragma unroll
    for (int n=0;n<4;++n) acc[m][n] = (f4_t)0.f;

  bf8_t bfr[4][2];

  auto mfma2 = [&](int m0, const bf8_t a00, const bf8_t a01,
                   const bf8_t a10, const bf8_t a11){
    __builtin_amdgcn_s_setprio(1);
    #pragma unroll
    for (int n=0;n<4;++n){
      acc[m0][n]   = __builtin_amdgcn_mfma_f32_16x16x32_bf16(a00, bfr[n][0], acc[m0][n],   0,0,0);
      acc[m0][n]   = __builtin_amdgcn_mfma_f32_16x16x32_bf16(a01, bfr[n][1], acc[m0][n],   0,0,0);
      acc[m0+1][n] = __builtin_amdgcn_mfma_f32_16x16x32_bf16(a10, bfr[n][0], acc[m0+1][n], 0,0,0);
      acc[m0+1][n] = __builtin_amdgcn_mfma_f32_16x16x32_bf16(a11, bfr[n][1], acc[m0+1][n], 0,0,0);
    }
    __builtin_amdgcn_s_setprio(0);
  };

  auto phase12 = [&](int buf, auto&& stg){
    #pragma unroll
    for (int n=0;n<4;++n){ bfr[n][0]=rdB(buf,n,0); bfr[n][1]=rdB(buf,n,1); }
    const bf8_t a00=rdA(buf,0,0), a01=rdA(buf,0,1), a10=rdA(buf,1,0), a11=rdA(buf,1,1);
    stg();
    asm volatile("s_barrier" ::: "memory");
    mfma2(0, a00,a01,a10,a11);
    asm volatile("s_barrier" ::: "memory");
  };
  auto phase4 = [&](int buf, int m0, auto&& stg, bool vm){
    const bf8_t a00=rdA(buf,m0,0), a01=rdA(buf,m0,1), a10=rdA(buf,m0+1,0), a11=rdA(buf,m0+1,1);
    stg();
    if (vm){
      __builtin_amdgcn_sched_barrier(0);
      asm volatile("s_waitcnt vmcnt(4)" ::: "memory");
    }
    asm volatile("s_barrier" ::: "memory");
    mfma2(m0, a00,a01,a10,a11);
    asm volatile("s_barrier" ::: "memory");
  };

  // prologue: B(0), B(1) staged; A(0) reg-loaded+written (auto-waits drain B too)
  stB(0,0,0); stB(0,0,1); stB(1,1,0); stB(1,1,1);
  ldA(0,0); wrA(0,0); ldA(0,1); wrA(0,1);
  asm volatile("s_waitcnt lgkmcnt(0)" ::: "memory");
  asm volatile("s_waitcnt vmcnt(0)" ::: "memory");
  asm volatile("s_barrier" ::: "memory");

  const int NIT = KT >> 1;
  for (int it=0; it<NIT; ++it){
    const int t0 = 2*it, t1 = t0+1;
    const int tN  = (t0+2 < KT) ? t0+2 : KT-1;   // clamped: dead-region write on last iter
    const int tB3 = (t1+2 < KT) ? t1+2 : KT-1;

    phase12(0,      [&]{ ldA(t1,0); });                               // P0
    phase4 (0, 2,   [&]{ wrA(1,0); ldA(t1,1); }, false);              // P1
    phase4 (0, 4,   [&]{ wrA(1,1); stB(0,tN,0); }, false);            // P2
    phase4 (0, 6,   [&]{ stB(0,tN,1);
                         asm volatile("s_waitcnt lgkmcnt(0)":::"memory"); }, true);  // P3
    phase12(1,      [&]{ ldA(tN,0); });                               // P4
    phase4 (1, 2,   [&]{ wrA(0,0); ldA(tN,1); }, false);              // P5
    phase4 (1, 4,   [&]{ wrA(0,1); stB(1,tB3,0); }, false);           // P6
    phase4 (1, 6,   [&]{ stB(1,tB3,1);
                         asm volatile("s_waitcnt lgkmcnt(0)":::"memory"); }, true);  // P7
  }

  #pragma unroll
  for (int n=0;n<4;++n){
    const int col = bn0 + wn + n*16 + fr;
    const float bv = bias[col];
    #pragma unroll
    for (int m=0;m<8;++m){
      #pragma unroll
      for (int j=0;j<4;++j){
        const int row = bm0 + wm + m*16 + kg*4 + j;
        float v = fmaxf(acc[m][n][j] + bv, 0.f);
        Cp[(size_t)row*N + col] = f2bf(v);
      }
    }
  }
}

// ------------- bf16 BT GEMM 64x64 (high-occupancy, small recurrent GEMMs; r3-proven) -------------
template<bool OUT_BF16, bool BIAS>
__global__ __launch_bounds__(256) void gemm64(
    const unsigned short* __restrict__ A,
    const unsigned short* __restrict__ Bw,
    const float* __restrict__ bias,
    void* __restrict__ Cp,
    int N, int K, int nwg)
{
  __shared__ __align__(16) unsigned short As[64*64];
  __shared__ __align__(16) unsigned short Bs[64*64];
  const int tid = threadIdx.x, lane = tid & 63, wave = tid >> 6;
  const int bid = blockIdx.x;
  const int swz = (bid & 7)*(nwg >> 3) + (bid >> 3);
  const int nx  = N >> 6;
  const int lnx = 31 - __clz(nx);
  const int bm0 = (swz >> lnx) << 6;
  const int bn0 = (swz & (nx-1)) << 6;

  const int r8  = lane >> 3;
  const int gsw = ((lane & 7) ^ r8) * 8;
  const unsigned short* Ab = A  + (size_t)(bm0 + wave*16 + r8)*K + gsw;
  const unsigned short* Bb = Bw + (size_t)(bn0 + wave*16 + r8)*K + gsw;
  unsigned short* la = As + wave*1024;
  unsigned short* lb = Bs + wave*1024;

  f4_t acc[2][2];
  #pragma unroll
  for (int m=0;m<2;++m)
    #pragma unroll
    for (int n=0;n<2;++n) acc[m][n] = (f4_t)0.f;

  const int KT = K >> 6;
  const int fr = lane & 15, kg = lane >> 4;
  const int wm = (wave & 1)*32, wn = (wave >> 1)*32;

  for (int kt = 0; kt < KT; ++kt){
    if (kt) __syncthreads();
    const size_t ko = (size_t)kt*64;
    #pragma unroll
    for (int q = 0; q < 2; ++q){
      gload16(Ab + ko + (size_t)q*8*K, la + q*512);
      gload16(Bb + ko + (size_t)q*8*K, lb + q*512);
    }
    __syncthreads();
    #pragma unroll
    for (int kk = 0; kk < 2; ++kk){
      bf8_t af[2], bf_[2];
      #pragma unroll
      for (int m=0;m<2;++m){
        const int r = wm+m*16+fr;
        af[m]  = *(const bf8_t*)&As[r*64 + (((kk*4+kg) ^ (r&7))*8)];
      }
      #pragma unroll
      for (int n=0;n<2;++n){
        const int r = wn+n*16+fr;
        bf_[n] = *(const bf8_t*)&Bs[r*64 + (((kk*4+kg) ^ (r&7))*8)];
      }
      #pragma unroll
      for (int m=0;m<2;++m)
        #pragma unroll
        for (int n=0;n<2;++n)
          acc[m][n] = __builtin_amdgcn_mfma_f32_16x16x32_bf16(af[m], bf_[n], acc[m][n], 0,0,0);
    }
  }

  #pragma unroll
  for (int n=0;n<2;++n){
    const int col = bn0 + wn + n*16 + fr;
    float bv = 0.f;
    if constexpr (BIAS) bv = bias[col];
    #pragma unroll
    for (int m=0;m<2;++m){
      #pragma unroll
      for (int j=0;j<4;++j){
        const int row = bm0 + wm + m*16 + kg*4 + j;
        float v = acc[m][n][j] + bv;
        if constexpr (OUT_BF16) ((unsigned short*)Cp)[(size_t)row*N + col] = f2bf(v);
        else                    ((float*)Cp)[(size_t)row*N + col] = v;
      }
    }
  }
}

// ---------------- fused LN + LSTM elementwise step (one WG per batch row; r3-proven) ----------------
__global__ __launch_bounds__(256) void lstm_step(
  const unsigned short* __restrict__ X, const unsigned short* __restrict__ Gh,
  const float* __restrict__ c_src, float* __restrict__ c_dst,
  const float* __restrict__ g_ih, const float* __restrict__ b_ih,
  const float* __restrict__ g_hh, const float* __restrict__ b_hh,
  const float* __restrict__ g_c,  const float* __restrict__ b_c,
  unsigned short* __restrict__ h_out, unsigned short* __restrict__ lstm_out,
  int t)
{
  const int b = blockIdx.x, tid = threadIdx.x;
  __shared__ float xs[GATE];
  __shared__ float gs[GATE];
  __shared__ float red[32];
  const unsigned short* xrow = X  + ((size_t)b*SEQ + t)*GATE;
  const unsigned short* grow = Gh + (size_t)b*GATE;
  u16x8 xv = *(const u16x8*)&xrow[tid*8];
  u16x8 gv = *(const u16x8*)&grow[tid*8];
  float sx=0,sx2=0,sg=0,sg2=0;
  #pragma unroll
  for (int j=0;j<8;++j){
    float x = bf2f(xv[j]), g = bf2f(gv[j]);
    xs[tid*8+j]=x; gs[tid*8+j]=g;
    sx += x; sx2 += x*x; sg += g; sg2 += g*g;
  }
  #pragma unroll
  for (int m=32;m;m>>=1){
    sx += __shfl_xor(sx,m); sx2 += __shfl_xor(sx2,m);
    sg += __shfl_xor(sg,m); sg2 += __shfl_xor(sg2,m);
  }
  const int w = tid>>6;
  if ((tid&63)==0){ red[w]=sx; red[4+w]=sx2; red[8+w]=sg; red[12+w]=sg2; }
  __syncthreads();
  sx  = red[0]+red[1]+red[2]+red[3];
  sx2 = red[4]+red[5]+red[6]+red[7];
  sg  = red[8]+red[9]+red[10]+red[11];
  sg2 = red[12]+red[13]+red[14]+red[15];
  const float mX = sx*(1.f/GATE), mH = sg*(1.f/GATE);
  const float rX = rsqrtf(sx2*(1.f/GATE)-mX*mX+EPSV);
  const float rH = rsqrtf(sg2*(1.f/GATE)-mH*mH+EPSV);

  float cN[2], xo[2]; float sc=0, sc2=0;
  #pragma unroll
  for (int rep=0;rep<2;++rep){
    const int n = tid + rep*256;
    const int ni=n, nf=n+HID, ng=n+2*HID, no=n+3*HID;
    float gi = (xs[ni]-mX)*rX*g_ih[ni]+b_ih[ni] + (gs[ni]-mH)*rH*g_hh[ni]+b_hh[ni];
    float gf = (xs[nf]-mX)*rX*g_ih[nf]+b_ih[nf] + (gs[nf]-mH)*rH*g_hh[nf]+b_hh[nf];
    float gg = (xs[ng]-mX)*rX*g_ih[ng]+b_ih[ng] + (gs[ng]-mH)*rH*g_hh[ng]+b_hh[ng];
    float go = (xs[no]-mX)*rX*g_ih[no]+b_ih[no] + (gs[no]-mH)*rH*g_hh[no]+b_hh[no];
    float co = c_src[(size_t)b*HID + n];
    float cn = sigm(gf)*co + sigm(gi)*tanh_f(gg);
    cN[rep]=cn; xo[rep]=go;
    sc += cn; sc2 += cn*cn;
  }
  #pragma unroll
  for (int m=32;m;m>>=1){ sc += __shfl_xor(sc,m); sc2 += __shfl_xor(sc2,m); }
  if ((tid&63)==0){ red[16+w]=sc; red[20+w]=sc2; }
  __syncthreads();
  sc  = red[16]+red[17]+red[18]+red[19];
  sc2 = red[20]+red[21]+red[22]+red[23];
  const float mC = sc*(1.f/HID);
  const float rC = rsqrtf(sc2*(1.f/HID)-mC*mC+EPSV);
  #pragma unroll
  for (int rep=0;rep<2;++rep){
    const int n = tid + rep*256;
    float hN = sigm(xo[rep])*tanh_f((cN[rep]-mC)*rC*g_c[n]+b_c[n]);
    c_dst[(size_t)b*HID+n] = cN[rep];
    unsigned short hbv = f2bf(hN);
    h_out[(size_t)b*HID+n] = hbv;
    lstm_out[((size_t)b*SEQ+t)*HID+n] = hbv;
  }
}

// ---------------- fused attention: scores -> softmax -> pooled -> scalar out ----------------
__global__ __launch_bounds__(256) void attn_out_k(
  const float* __restrict__ q, const unsigned short* __restrict__ Km,
  const unsigned short* __restrict__ lo_all,
  const float* __restrict__ u, const float* __restrict__ Cc,
  float* __restrict__ out)
{
  const int b = blockIdx.x, tid = threadIdx.x;
  __shared__ float qs[DK];
  __shared__ float sc[NH][SEQ];
  __shared__ float at[NH][SEQ];
  __shared__ float red[4];
  for (int i=tid; i<DK; i+=256) qs[i] = q[(size_t)b*DK + i];
  __syncthreads();
  {
    const int p = tid>>2, sub = tid&3, h = p>>4, s = p&15;
    const unsigned short* krow = Km + ((size_t)b*SEQ + s)*DK + h*DH + sub*32;
    const float* qh = &qs[h*DH + sub*32];
    float part = 0.f;
    #pragma unroll
    for (int c8=0;c8<4;++c8){
      u16x8 kv = *(const u16x8*)(krow + c8*8);
      #pragma unroll
      for (int j=0;j<8;++j) part += qh[c8*8+j]*bf2f(kv[j]);
    }
    part += __shfl_xor(part,1); part += __shfl_xor(part,2);
    if (sub==0) sc[h][s] = part * 0.08838834764831845f;
  }
  __syncthreads();
  if (tid < 64){
    const int h = tid>>4;
    float v = sc[h][tid&15], mx = v;
    #pragma unroll
    for (int m=1;m<16;m<<=1) mx = fmaxf(mx, __shfl_xor(mx,m));
    float e = __expf(v-mx), se = e;
    #pragma unroll
    for (int m=1;m<16;m<<=1) se += __shfl_xor(se,m);
    at[h][tid&15] = e/se;
  }
  __syncthreads();
  float accum = 0.f;
  #pragma unroll
  for (int it=0; it<4; ++it){
    const int idx = it*256 + tid;
    const int h = idx>>8, d0 = (idx&255)*2;
    const unsigned short* lo = lo_all + (size_t)b*SEQ*HID + d0;
    float p0=0.f, p1=0.f;
    #pragma unroll
    for (int s=0;s<16;++s){
      unsigned int pr = *(const unsigned int*)(lo + s*HID);
      float a = at[h][s];
      p0 += a*bf2f((unsigned short)(pr&0xffffu));
      p1 += a*bf2f((unsigned short)(pr>>16));
    }
    accum += u[h*HID+d0]*p0 + u[h*HID+d0+1]*p1;
  }
  #pragma unroll
  for (int m=32;m;m>>=1) accum += __shfl_xor(accum,m);
  if ((tid&63)==0) red[tid>>6] = accum;
  __syncthreads();
  if (tid==0) out[1+b] = red[0]+red[1]+red[2]+red[3] + Cc[0];
}

__global__ __launch_bounds__(256) void loss_k(const float* __restrict__ label, float* __restrict__ out){
  const int tid = threadIdx.x;
  __shared__ float red[4];
  float s = 0.f;
  for (int b=tid; b<B_SZ; b+=256){
    float d = out[1+b] - label[(size_t)b*SEQ + (SEQ-1)];
    s += d*d;
  }
  #pragma unroll
  for (int m=32;m;m>>=1) s += __shfl_xor(s,m);
  if ((tid&63)==0) red[tid>>6]=s;
  __syncthreads();
  if (tid==0) out[0] = (red[0]+red[1]+red[2]+red[3]) * (1.f/B_SZ);
}

__global__ __launch_bounds__(256) void cvt_bf16_k(const float* __restrict__ in, unsigned short* __restrict__ o, int n){
  int i = (blockIdx.x*256 + threadIdx.x)*4;
  if (i < n){
    f4_t v = *(const f4_t*)&in[i];
    u16x4 w;
    #pragma unroll
    for (int j=0;j<4;++j) w[j] = f2bf(v[j]);
    *(u16x4*)&o[i] = w;
  }
}

// -------- fold wout/out_W/wv into u[h,d] and scalar C (exact: sum(attn)==1) --------
__global__ __launch_bounds__(256) void fold_we_k(
  const float* __restrict__ wout_W, const float* __restrict__ out_W, float* __restrict__ we)
{
  const int j = blockIdx.x*256 + threadIdx.x;
  float s=0.f;
  for (int m=0;m<512;++m) s += out_W[m]*wout_W[(size_t)m*2048+j];
  we[j]=s;
}
__global__ __launch_bounds__(256) void fold_u_k(
  const float* __restrict__ we, const float* __restrict__ wv_W, float* __restrict__ u)
{
  const int o = blockIdx.x*256 + threadIdx.x;
  const int h = o>>9, d = o&511;
  const float* wv = wv_W + (size_t)h*262144 + d;
  const float* wp = we + h*512;
  float s=0.f;
  for (int k=0;k<512;++k) s += wp[k]*wv[(size_t)k*512];
  u[o]=s;
}
__global__ __launch_bounds__(256) void fold_c_k(
  const float* __restrict__ we, const float* __restrict__ wv_b,
  const float* __restrict__ out_W, const float* __restrict__ wout_b,
  const float* __restrict__ out_b, float* __restrict__ Cc)
{
  const int tid = threadIdx.x;
  __shared__ float red[4];
  float s=0.f;
  for (int j=tid;j<2048;j+=256) s += we[j]*wv_b[j];
  for (int m=tid;m<512;m+=256)  s += out_W[m]*wout_b[m];
  #pragma unroll
  for (int m=32;m;m>>=1) s += __shfl_xor(s,m);
  if ((tid&63)==0) red[tid>>6]=s;
  __syncthreads();
  if (tid==0) Cc[0] = red[0]+red[1]+red[2]+red[3] + out_b[0];
}

extern "C" void kernel_launch(void* const* d_in, const int* in_sizes, int n_in,
                              void* d_out, int out_size, void* d_ws, size_t ws_size,
                              hipStream_t stream)
{
  const float* visual = (const float*)d_in[0];
  const float* text   = (const float*)d_in[1];
  const float* user_  = (const float*)d_in[2];
  const float* cat_   = (const float*)d_in[3];
  const float* label  = (const float*)d_in[4];
  const float* h0     = (const float*)d_in[5];
  const float* c0     = (const float*)d_in[6];
  const float* fus_W  = (const float*)d_in[7];
  const float* fus_b  = (const float*)d_in[8];
  const float* W_ih   = (const float*)d_in[9];
  const float* W_hh   = (const float*)d_in[10];
  const float* g_ih   = (const float*)d_in[11];
  const float* b_ih   = (const float*)d_in[12];
  const float* g_hh   = (const float*)d_in[13];
  const float* b_hh   = (const float*)d_in[14];
  const float* g_c    = (const float*)d_in[15];
  const float* b_c    = (const float*)d_in[16];
  const float* wq_W   = (const float*)d_in[17];
  const float* wq_b   = (const float*)d_in[18];
  const float* wk_W   = (const float*)d_in[19];
  const float* wk_b   = (const float*)d_in[20];
  const float* wv_W   = (const float*)d_in[21];
  const float* wv_b   = (const float*)d_in[22];
  const float* wout_W = (const float*)d_in[23];
  const float* wout_b = (const float*)d_in[24];
  const float* out_W  = (const float*)d_in[25];
  const float* out_b  = (const float*)d_in[26];
  (void)in_sizes; (void)n_in; (void)out_size; (void)ws_size;

  char* base = (char*)d_ws; size_t off = 0;
  auto alloc = [&](size_t n)->void*{ void* p = base+off; off += n; off = (off+255)&~(size_t)255; return p; };
  unsigned short* X     = (unsigned short*)alloc((size_t)32768*2048*2);   // 128 MB
  unsigned short* vt    = (unsigned short*)alloc((size_t)32768*1024*2);   // 64 MB
  unsigned short* lo    = (unsigned short*)alloc((size_t)32768*512*2);    // 32 MB
  unsigned short* Km    = (unsigned short*)alloc((size_t)32768*512*2);    // 32 MB
  unsigned short* Gh    = (unsigned short*)alloc((size_t)2048*2048*2);    // 8 MB
  float*          cws   = (float*)         alloc((size_t)2048*512*4);     // 4 MB
  unsigned short* hb    = (unsigned short*)alloc((size_t)2048*512*2);
  float*          qb    = (float*)         alloc((size_t)2048*512*4);
  unsigned short* fusWb = (unsigned short*)alloc((size_t)1024*4096*2);
  unsigned short* Wihb  = (unsigned short*)alloc((size_t)2048*1024*2);
  unsigned short* Whhb  = (unsigned short*)alloc((size_t)2048*512*2);
  unsigned short* wqb   = (unsigned short*)alloc((size_t)512*512*2);
  unsigned short* wkb   = (unsigned short*)alloc((size_t)512*512*2);
  float*          we_ws = (float*)         alloc(2048*4);
  float*          u_ws  = (float*)         alloc(2048*4);
  float*          C_ws  = (float*)         alloc(256);

  // weight conversions + folds
  cvt_bf16_k<<<dim3(4096), dim3(256), 0, stream>>>(fus_W, fusWb, 1024*4096);
  cvt_bf16_k<<<dim3(2048), dim3(256), 0, stream>>>(W_ih,  Wihb,  2048*1024);
  cvt_bf16_k<<<dim3(1024), dim3(256), 0, stream>>>(W_hh,  Whhb,  2048*512);
  cvt_bf16_k<<<dim3(256),  dim3(256), 0, stream>>>(wq_W,  wqb,   512*512);
  cvt_bf16_k<<<dim3(256),  dim3(256), 0, stream>>>(wk_W,  wkb,   512*512);
  cvt_bf16_k<<<dim3(1024), dim3(256), 0, stream>>>(h0,    hb,    2048*512);
  fold_we_k<<<dim3(8), dim3(256), 0, stream>>>(wout_W, out_W, we_ws);
  fold_u_k <<<dim3(8), dim3(256), 0, stream>>>(we_ws, wv_W, u_ws);
  fold_c_k <<<dim3(1), dim3(256), 0, stream>>>(we_ws, wv_b, out_W, wout_b, out_b, C_ws);

  // GEMM1 (fused fp32-A cvt, 8-phase): vt = relu(mods @ fus_W^T + fus_b)  M=32768 N=1024 K=4096
  gemm8pf<<<dim3(512), dim3(512), 0, stream>>>(
      visual, text, user_, cat_, fusWb, fus_b, vt, 1024, 4096, 512);
  // GEMM2: X = vt @ W_ih^T  (bf16 out; LN renormalizes)  M=32768 N=2048 K=1024
  gemm8p<true,false,false><<<dim3(1024), dim3(512), 0, stream>>>(
      vt, Wihb, nullptr, X, 2048, 1024, 1024);

  // recurrence (r3-proven: 64x64 tiles -> 1024 WGs, 4/CU)
  for (int t=0; t<SEQ; ++t){
    gemm64<true,false><<<dim3(1024), dim3(256), 0, stream>>>(
        hb, Whhb, nullptr, Gh, 2048, 512, 1024);
    lstm_step<<<dim3(2048), dim3(256), 0, stream>>>(
        X, Gh, (t==0 ? c0 : cws), cws, g_ih, b_ih, g_hh, b_hh, g_c, b_c, hb, lo, t);
  }

  // q = hn @ wq_W^T + wq_b   (fp32 out)  M=2048 N=512 K=512
  gemm64<false,true><<<dim3(256), dim3(256), 0, stream>>>(
      hb, wqb, wq_b, qb, 512, 512, 256);
  // Kmat = lstm_out @ wk_W^T + wk_b  (bf16 out)  M=32768 N=512 K=512
  gemm8p<true,true,false><<<dim3(256), dim3(512), 0, stream>>>(
      lo, wkb, wk_b, Km, 512, 512, 256);

  attn_out_k<<<dim3(2048), dim3(256), 0, stream>>>(qb, Km, lo, u_ws, C_ws, (float*)d_out);
  loss_k<<<dim3(1), dim3(256), 0, stream>>>(label, (float*)d_out);
}

// Round 9
// 945.506 us; speedup vs baseline: 1.0621x; 1.0347x over previous
//
#include <hip/hip_runtime.h>
#include <cstdint>

#define B_SZ 2048
#define SEQ  16
#define DIM  1024
#define HID  512
#define DK   512
#define NH   4
#define DH   128
#define GATE 2048
#define EPSV 1e-5f

typedef __bf16 bf8_t __attribute__((ext_vector_type(8)));
typedef float  f4_t  __attribute__((ext_vector_type(4)));
typedef unsigned short u16x8 __attribute__((ext_vector_type(8)));
typedef unsigned short u16x4 __attribute__((ext_vector_type(4)));

__device__ __forceinline__ unsigned short f2bf(float f){
  __bf16 h = (__bf16)f;                       // RNE
  return __builtin_bit_cast(unsigned short, h);
}
__device__ __forceinline__ float bf2f(unsigned short u){
  return __builtin_bit_cast(float, ((unsigned int)u) << 16);
}
__device__ __forceinline__ float sigm(float x){ return 1.f/(1.f+__expf(-x)); }
__device__ __forceinline__ float tanh_f(float x){ return 1.f - 2.f/(__expf(2.f*x)+1.f); }

__device__ __forceinline__ void gload16(const void* g, void* l){
  __builtin_amdgcn_global_load_lds(
      (const __attribute__((address_space(1))) void*)g,
      (__attribute__((address_space(3))) void*)l, 16, 0, 0);
}

// ================= 256x256 8-phase pipelined BT GEMM, bf16 A (r7-proven 968 TF) =================
template<bool OUT_BF16, bool BIAS, bool RELU>
__global__ __launch_bounds__(512, 1) void gemm8p(
    const unsigned short* __restrict__ A,
    const unsigned short* __restrict__ Bw,
    const float* __restrict__ bias,
    void* __restrict__ Cp,
    int N, int K, int nwg)
{
  __shared__ __align__(16) unsigned short As[2][256*64];
  __shared__ __align__(16) unsigned short Bs[2][256*64];
  const int tid = threadIdx.x, lane = tid & 63, w = tid >> 6;
  const int bid = blockIdx.x;
  const int swz = (bid & 7)*(nwg >> 3) + (bid >> 3);   // nwg % 8 == 0 at all call sites
  const int nx  = N >> 8;
  const int lnx = 31 - __clz(nx);
  const int bm0 = (swz >> lnx) << 8;
  const int bn0 = (swz & (nx-1)) << 8;

  const int l8  = lane >> 3;
  const int gsw = (lane & 7) ^ l8;
  const int fr  = lane & 15, kg = lane >> 4;
  const int wm  = (w >> 2)*128, wn = (w & 3)*64;
  const int KT  = K >> 6;

  auto stA = [&](int buf, int kt, int h){
    #pragma unroll
    for (int c=0;c<2;++c){
      const int rb = h*128 + c*64 + w*8;
      gload16(A + (size_t)(bm0 + rb + l8)*K + (size_t)kt*64 + gsw*8, &As[buf][rb*64]);
    }
  };
  auto stB = [&](int buf, int kt, int h){
    #pragma unroll
    for (int c=0;c<2;++c){
      const int rb = h*128 + c*64 + w*8;
      gload16(Bw + (size_t)(bn0 + rb + l8)*K + (size_t)kt*64 + gsw*8, &Bs[buf][rb*64]);
    }
  };
  auto rdA = [&](int buf, int m, int kk)->bf8_t{
    return *(const bf8_t*)&As[buf][(wm + m*16 + fr)*64 + (((kk*4+kg) ^ (fr&7))*8)];
  };
  auto rdB = [&](int buf, int n, int kk)->bf8_t{
    return *(const bf8_t*)&Bs[buf][(wn + n*16 + fr)*64 + (((kk*4+kg) ^ (fr&7))*8)];
  };

  f4_t acc[8][4];
  #pragma unroll
  for (int m=0;m<8;++m)
    #pragma unroll
    for (int n=0;n<4;++n) acc[m][n] = (f4_t)0.f;

  bf8_t bfr[4][2];

  auto mfma2 = [&](int m0, const bf8_t a00, const bf8_t a01,
                   const bf8_t a10, const bf8_t a11){
    __builtin_amdgcn_s_setprio(1);
    #pragma unroll
    for (int n=0;n<4;++n){
      acc[m0][n]   = __builtin_amdgcn_mfma_f32_16x16x32_bf16(a00, bfr[n][0], acc[m0][n],   0,0,0);
      acc[m0][n]   = __builtin_amdgcn_mfma_f32_16x16x32_bf16(a01, bfr[n][1], acc[m0][n],   0,0,0);
      acc[m0+1][n] = __builtin_amdgcn_mfma_f32_16x16x32_bf16(a10, bfr[n][0], acc[m0+1][n], 0,0,0);
      acc[m0+1][n] = __builtin_amdgcn_mfma_f32_16x16x32_bf16(a11, bfr[n][1], acc[m0+1][n], 0,0,0);
    }
    __builtin_amdgcn_s_setprio(0);
  };

  auto phase12 = [&](int buf, auto&& stg){
    #pragma unroll
    for (int n=0;n<4;++n){ bfr[n][0]=rdB(buf,n,0); bfr[n][1]=rdB(buf,n,1); }
    const bf8_t a00=rdA(buf,0,0), a01=rdA(buf,0,1), a10=rdA(buf,1,0), a11=rdA(buf,1,1);
    stg();
    asm volatile("s_barrier" ::: "memory");
    mfma2(0, a00,a01,a10,a11);
    asm volatile("s_barrier" ::: "memory");
  };
  auto phase4 = [&](int buf, int m0, auto&& stg, bool vm){
    const bf8_t a00=rdA(buf,m0,0), a01=rdA(buf,m0,1), a10=rdA(buf,m0+1,0), a11=rdA(buf,m0+1,1);
    stg();
    if (vm){
      __builtin_amdgcn_sched_barrier(0);
      asm volatile("s_waitcnt vmcnt(4)" ::: "memory");
    }
    asm volatile("s_barrier" ::: "memory");
    mfma2(m0, a00,a01,a10,a11);
    asm volatile("s_barrier" ::: "memory");
  };

  stA(0,0,0); stA(0,0,1); stB(0,0,0); stB(0,0,1);
  stB(1,1,0); stB(1,1,1);
  __builtin_amdgcn_sched_barrier(0);
  asm volatile("s_waitcnt vmcnt(4)" ::: "memory");
  asm volatile("s_barrier" ::: "memory");

  const int NIT = KT >> 1;
  for (int it=0; it<NIT; ++it){
    const int t0 = 2*it, t1 = t0+1;
    const int tN  = (t0+2 < KT) ? t0+2 : KT-1;
    const int tB3 = (t1+2 < KT) ? t1+2 : KT-1;

    phase12(0,      [&]{ stA(1,t1,0);  });
    phase4 (0, 2,   [&]{ stA(1,t1,1);  }, false);
    phase4 (0, 4,   [&]{ stB(0,tN,0);  }, false);
    phase4 (0, 6,   [&]{ stB(0,tN,1);  }, true);
    phase12(1,      [&]{ stA(0,tN,0);  });
    phase4 (1, 2,   [&]{ stA(0,tN,1);  }, false);
    phase4 (1, 4,   [&]{ stB(1,tB3,0); }, false);
    phase4 (1, 6,   [&]{ stB(1,tB3,1); }, true);
  }

  #pragma unroll
  for (int n=0;n<4;++n){
    const int col = bn0 + wn + n*16 + fr;
    float bv = 0.f;
    if constexpr (BIAS) bv = bias[col];
    #pragma unroll
    for (int m=0;m<8;++m){
      #pragma unroll
      for (int j=0;j<4;++j){
        const int row = bm0 + wm + m*16 + kg*4 + j;
        float v = acc[m][n][j] + bv;
        if constexpr (RELU) v = fmaxf(v, 0.f);
        if constexpr (OUT_BF16) ((unsigned short*)Cp)[(size_t)row*N + col] = f2bf(v);
        else                    ((float*)Cp)[(size_t)row*N + col] = v;
      }
    }
  }
}

// ===== 256x256 8-phase GEMM, FUSED fp32->bf16 A, quarter-pipelined reg staging (r9) =====
// A staged in 64-row quarters: 8 f32/thread, 2 alternating reg sets (rgA even q, rgB odd q),
// ld issued 2 phases before its wr. LEDGER (in-order vmcnt forcing, m135):
//   buf1-A: ld q0@P6',q1@P7',q2@P0,q3@P1 -> wr q0@P0..q3@P3 ; lgkm@P3 (buf1 read P4+)
//   buf0-A: ld q0@P2,q1@P3,q2@P4,q3@P5  -> wr q0@P4..q3@P7 ; lgkm@P7 (buf0 read next P0)
//   B:      stB(0,tN)@P2/P3 ; stB(1,tB3)@P6/P7  (ld pinned BEFORE stB in-phase)
//   wr1q3@P3 waits ld1q3@P1 -> forces prev-P6/P7 stB(1,t1) complete  => buf1-B ready @P4. ✓
//   wr0q3@P7 waits ld0q3@P5 -> forces P2/P3 stB(0,tN) complete       => buf0-B ready @next P0. ✓
//   Writes target the buffer NOT being read in that phase-half; trail barriers order reuse. ✓
__global__ __launch_bounds__(512, 1) void gemm8pf(
    const float* __restrict__ A0, const float* __restrict__ A1,
    const float* __restrict__ A2, const float* __restrict__ A3,
    const unsigned short* __restrict__ Bw,
    const float* __restrict__ bias,
    unsigned short* __restrict__ Cp,
    int N, int K, int nwg)
{
  __shared__ __align__(16) unsigned short As[2][256*64];
  __shared__ __align__(16) unsigned short Bs[2][256*64];
  const int tid = threadIdx.x, lane = tid & 63, w = tid >> 6;
  const int bid = blockIdx.x;
  const int swz = (bid & 7)*(nwg >> 3) + (bid >> 3);
  const int nx  = N >> 8;
  const int lnx = 31 - __clz(nx);
  const int bm0 = (swz >> lnx) << 8;
  const int bn0 = (swz & (nx-1)) << 8;

  const int l8  = lane >> 3;
  const int gsw = (lane & 7) ^ l8;
  const int fr  = lane & 15, kg = lane >> 4;
  const int wm  = (w >> 2)*128, wn = (w & 3)*64;
  const int KT  = K >> 6;

  auto stB = [&](int buf, int kt, int h){
    #pragma unroll
    for (int c=0;c<2;++c){
      const int rb = h*128 + c*64 + w*8;
      gload16(Bw + (size_t)(bn0 + rb + l8)*K + (size_t)kt*64 + gsw*8, &Bs[buf][rb*64]);
    }
  };

  // quarter staging: row = q*64 + tid>>3 (64 rows/q), 8 f32 at chunk tid&7
  f4_t rgA[2], rgB[2];
  auto ldQ = [&](f4_t* rg, int kt, int q){
    const int kb = kt*64, si = kb >> 10, kc = kb & 1023;
    const float* Asel = si==0?A0 : si==1?A1 : si==2?A2 : A3;
    const float* p = Asel + (size_t)(bm0 + q*64 + (tid>>3))*1024 + kc + (tid&7)*8;
    rg[0] = *(const f4_t*)p; rg[1] = *(const f4_t*)(p+4);
  };
  auto wrQ = [&](const f4_t* rg, int buf, int q){
    const int R = q*64 + (tid>>3);
    const int g = (tid&7) ^ (R&7);          // same involution as rdA
    u16x8 wv;
    #pragma unroll
    for (int j=0;j<4;++j){ wv[j]=f2bf(rg[0][j]); wv[4+j]=f2bf(rg[1][j]); }
    *(u16x8*)&As[buf][R*64 + g*8] = wv;
  };

  auto rdA = [&](int buf, int m, int kk)->bf8_t{
    return *(const bf8_t*)&As[buf][(wm + m*16 + fr)*64 + (((kk*4+kg) ^ (fr&7))*8)];
  };
  auto rdB = [&](int buf, int n, int kk)->bf8_t{
    return *(const bf8_t*)&Bs[buf][(wn + n*16 + fr)*64 + (((kk*4+kg) ^ (fr&7))*8)];
  };

  f4_t acc[8][4];
  #pragma unroll
  for (int m=0;m<8;++m)
    #pragma unroll
    for (int n=0;n<4;++n) acc[m][n] = (f4_t)0.f;

  bf8_t bfr[4][2];

  auto mfma2 = [&](int m0, const bf8_t a00, const bf8_t a01,
                   const bf8_t a10, const bf8_t a11){
    __builtin_amdgcn_s_setprio(1);
    #pragma unroll
    for (int n=0;n<4;++n){
      acc[m0][n]   = __builtin_amdgcn_mfma_f32_16x16x32_bf16(a00, bfr[n][0], acc[m0][n],   0,0,0);
      acc[m0][n]   = __builtin_amdgcn_mfma_f32_16x16x32_bf16(a01, bfr[n][1], acc[m0][n],   0,0,0);
      acc[m0+1][n] = __builtin_amdgcn_mfma_f32_16x16x32_bf16(a10, bfr[n][0], acc[m0+1][n], 0,0,0);
      acc[m0+1][n] = __builtin_amdgcn_mfma_f32_16x16x32_bf16(a11, bfr[n][1], acc[m0+1][n], 0,0,0);
    }
    __builtin_amdgcn_s_setprio(0);
  };

  auto phase12 = [&](int buf, auto&& stg){
    #pragma unroll
    for (int n=0;n<4;++n){ bfr[n][0]=rdB(buf,n,0); bfr[n][1]=rdB(buf,n,1); }
    const bf8_t a00=rdA(buf,0,0), a01=rdA(buf,0,1), a10=rdA(buf,1,0), a11=rdA(buf,1,1);
    stg();
    asm volatile("s_barrier" ::: "memory");
    mfma2(0, a00,a01,a10,a11);
    asm volatile("s_barrier" ::: "memory");
  };
  auto phase4 = [&](int buf, int m0, auto&& stg){
    const bf8_t a00=rdA(buf,m0,0), a01=rdA(buf,m0,1), a10=rdA(buf,m0+1,0), a11=rdA(buf,m0+1,1);
    stg();
    asm volatile("s_barrier" ::: "memory");
    mfma2(m0, a00,a01,a10,a11);
    asm volatile("s_barrier" ::: "memory");
  };

  // prologue: B(0)->buf0, B(1)->buf1; A(0)->buf0 (serial); prime ld q0/q1 of tile 1
  stB(0,0,0); stB(0,0,1); stB(1,1,0); stB(1,1,1);
  ldQ(rgA,0,0); ldQ(rgB,0,1); wrQ(rgA,0,0); wrQ(rgB,0,1);
  ldQ(rgA,0,2); ldQ(rgB,0,3); wrQ(rgA,0,2); wrQ(rgB,0,3);
  ldQ(rgA,1,0); ldQ(rgB,1,1);
  asm volatile("s_waitcnt lgkmcnt(0)" ::: "memory");
  asm volatile("s_waitcnt vmcnt(2)" ::: "memory");   // all but primed ld q0/q1 (newest 2)
  asm volatile("s_barrier" ::: "memory");

  const int NIT = KT >> 1;
  for (int it=0; it<NIT; ++it){
    const int t1  = 2*it+1;
    const int tN  = (t1+1 < KT) ? t1+1 : KT-1;   // t0+2, clamped (dead writes last iter)
    const int tB3 = (t1+2 < KT) ? t1+2 : KT-1;

    // P0: wr1q0 (ld@prev P6), ld1q2
    phase12(0, [&]{ wrQ(rgA,1,0); ldQ(rgA,t1,2); });
    // P1: wr1q1, ld1q3
    phase4 (0, 2, [&]{ wrQ(rgB,1,1); ldQ(rgB,t1,3); });
    // P2: wr1q2, ld0q0, stB(0,tN,0)   [ld pinned before stB]
    phase4 (0, 4, [&]{ wrQ(rgA,1,2); ldQ(rgA,tN,0);
                       __builtin_amdgcn_sched_barrier(0); stB(0,tN,0); });
    // P3: wr1q3, ld0q1, stB(0,tN,1), lgkm  -> wr1q3's wait forces prev P6/P7 B(t1) done
    phase4 (0, 6, [&]{ wrQ(rgB,1,3); ldQ(rgB,tN,1);
                       __builtin_amdgcn_sched_barrier(0); stB(0,tN,1);
                       __builtin_amdgcn_sched_barrier(0);
                       asm volatile("s_waitcnt lgkmcnt(0)":::"memory"); });
    // P4: wr0q0 (ld@P2), ld0q2
    phase12(1, [&]{ wrQ(rgA,0,0); ldQ(rgA,tN,2); });
    // P5: wr0q1, ld0q3
    phase4 (1, 2, [&]{ wrQ(rgB,0,1); ldQ(rgB,tN,3); });
    // P6: wr0q2, ld1'q0, stB(1,tB3,0)
    phase4 (1, 4, [&]{ wrQ(rgA,0,2); ldQ(rgA,tB3,0);
                       __builtin_amdgcn_sched_barrier(0); stB(1,tB3,0); });
    // P7: wr0q3, ld1'q1, stB(1,tB3,1), lgkm -> wr0q3's wait forces P2/P3 B(tN) done
    phase4 (1, 6, [&]{ wrQ(rgB,0,3); ldQ(rgB,tB3,1);
                       __builtin_amdgcn_sched_barrier(0); stB(1,tB3,1);
                       __builtin_amdgcn_sched_barrier(0);
                       asm volatile("s_waitcnt lgkmcnt(0)":::"memory"); });
  }

  #pragma unroll
  for (int n=0;n<4;++n){
    const int col = bn0 + wn + n*16 + fr;
    const float bv = bias[col];
    #pragma unroll
    for (int m=0;m<8;++m){
      #pragma unroll
      for (int j=0;j<4;++j){
        const int row = bm0 + wm + m*16 + kg*4 + j;
        float v = fmaxf(acc[m][n][j] + bv, 0.f);
        Cp[(size_t)row*N + col] = f2bf(v);
      }
    }
  }
}

// ------------- bf16 BT GEMM 64x64 (high-occupancy, small recurrent GEMMs; r3-proven) -------------
template<bool OUT_BF16, bool BIAS>
__global__ __launch_bounds__(256) void gemm64(
    const unsigned short* __restrict__ A,
    const unsigned short* __restrict__ Bw,
    const float* __restrict__ bias,
    void* __restrict__ Cp,
    int N, int K, int nwg)
{
  __shared__ __align__(16) unsigned short As[64*64];
  __shared__ __align__(16) unsigned short Bs[64*64];
  const int tid = threadIdx.x, lane = tid & 63, wave = tid >> 6;
  const int bid = blockIdx.x;
  const int swz = (bid & 7)*(nwg >> 3) + (bid >> 3);
  const int nx  = N >> 6;
  const int lnx = 31 - __clz(nx);
  const int bm0 = (swz >> lnx) << 6;
  const int bn0 = (swz & (nx-1)) << 6;

  const int r8  = lane >> 3;
  const int gsw = ((lane & 7) ^ r8) * 8;
  const unsigned short* Ab = A  + (size_t)(bm0 + wave*16 + r8)*K + gsw;
  const unsigned short* Bb = Bw + (size_t)(bn0 + wave*16 + r8)*K + gsw;
  unsigned short* la = As + wave*1024;
  unsigned short* lb = Bs + wave*1024;

  f4_t acc[2][2];
  #pragma unroll
  for (int m=0;m<2;++m)
    #pragma unroll
    for (int n=0;n<2;++n) acc[m][n] = (f4_t)0.f;

  const int KT = K >> 6;
  const int fr = lane & 15, kg = lane >> 4;
  const int wm = (wave & 1)*32, wn = (wave >> 1)*32;

  for (int kt = 0; kt < KT; ++kt){
    if (kt) __syncthreads();
    const size_t ko = (size_t)kt*64;
    #pragma unroll
    for (int q = 0; q < 2; ++q){
      gload16(Ab + ko + (size_t)q*8*K, la + q*512);
      gload16(Bb + ko + (size_t)q*8*K, lb + q*512);
    }
    __syncthreads();
    #pragma unroll
    for (int kk = 0; kk < 2; ++kk){
      bf8_t af[2], bf_[2];
      #pragma unroll
      for (int m=0;m<2;++m){
        const int r = wm+m*16+fr;
        af[m]  = *(const bf8_t*)&As[r*64 + (((kk*4+kg) ^ (r&7))*8)];
      }
      #pragma unroll
      for (int n=0;n<2;++n){
        const int r = wn+n*16+fr;
        bf_[n] = *(const bf8_t*)&Bs[r*64 + (((kk*4+kg) ^ (r&7))*8)];
      }
      #pragma unroll
      for (int m=0;m<2;++m)
        #pragma unroll
        for (int n=0;n<2;++n)
          acc[m][n] = __builtin_amdgcn_mfma_f32_16x16x32_bf16(af[m], bf_[n], acc[m][n], 0,0,0);
    }
  }

  #pragma unroll
  for (int n=0;n<2;++n){
    const int col = bn0 + wn + n*16 + fr;
    float bv = 0.f;
    if constexpr (BIAS) bv = bias[col];
    #pragma unroll
    for (int m=0;m<2;++m){
      #pragma unroll
      for (int j=0;j<4;++j){
        const int row = bm0 + wm + m*16 + kg*4 + j;
        float v = acc[m][n][j] + bv;
        if constexpr (OUT_BF16) ((unsigned short*)Cp)[(size_t)row*N + col] = f2bf(v);
        else                    ((float*)Cp)[(size_t)row*N + col] = v;
      }
    }
  }
}

// ---------------- fused LN + LSTM elementwise step (one WG per batch row; r3-proven) ----------------
__global__ __launch_bounds__(256) void lstm_step(
  const unsigned short* __restrict__ X, const unsigned short* __restrict__ Gh,
  const float* __restrict__ c_src, float* __restrict__ c_dst,
  const float* __restrict__ g_ih, const float* __restrict__ b_ih,
  const float* __restrict__ g_hh, const float* __restrict__ b_hh,
  const float* __restrict__ g_c,  const float* __restrict__ b_c,
  unsigned short* __restrict__ h_out, unsigned short* __restrict__ lstm_out,
  int t)
{
  const int b = blockIdx.x, tid = threadIdx.x;
  __shared__ float xs[GATE];
  __shared__ float gs[GATE];
  __shared__ float red[32];
  const unsigned short* xrow = X  + ((size_t)b*SEQ + t)*GATE;
  const unsigned short* grow = Gh + (size_t)b*GATE;
  u16x8 xv = *(const u16x8*)&xrow[tid*8];
  u16x8 gv = *(const u16x8*)&grow[tid*8];
  float sx=0,sx2=0,sg=0,sg2=0;
  #pragma unroll
  for (int j=0;j<8;++j){
    float x = bf2f(xv[j]), g = bf2f(gv[j]);
    xs[tid*8+j]=x; gs[tid*8+j]=g;
    sx += x; sx2 += x*x; sg += g; sg2 += g*g;
  }
  #pragma unroll
  for (int m=32;m;m>>=1){
    sx += __shfl_xor(sx,m); sx2 += __shfl_xor(sx2,m);
    sg += __shfl_xor(sg,m); sg2 += __shfl_xor(sg2,m);
  }
  const int w = tid>>6;
  if ((tid&63)==0){ red[w]=sx; red[4+w]=sx2; red[8+w]=sg; red[12+w]=sg2; }
  __syncthreads();
  sx  = red[0]+red[1]+red[2]+red[3];
  sx2 = red[4]+red[5]+red[6]+red[7];
  sg  = red[8]+red[9]+red[10]+red[11];
  sg2 = red[12]+red[13]+red[14]+red[15];
  const float mX = sx*(1.f/GATE), mH = sg*(1.f/GATE);
  const float rX = rsqrtf(sx2*(1.f/GATE)-mX*mX+EPSV);
  const float rH = rsqrtf(sg2*(1.f/GATE)-mH*mH+EPSV);

  float cN[2], xo[2]; float sc=0, sc2=0;
  #pragma unroll
  for (int rep=0;rep<2;++rep){
    const int n = tid + rep*256;
    const int ni=n, nf=n+HID, ng=n+2*HID, no=n+3*HID;
    float gi = (xs[ni]-mX)*rX*g_ih[ni]+b_ih[ni] + (gs[ni]-mH)*rH*g_hh[ni]+b_hh[ni];
    float gf = (xs[nf]-mX)*rX*g_ih[nf]+b_ih[nf] + (gs[nf]-mH)*rH*g_hh[nf]+b_hh[nf];
    float gg = (xs[ng]-mX)*rX*g_ih[ng]+b_ih[ng] + (gs[ng]-mH)*rH*g_hh[ng]+b_hh[ng];
    float go = (xs[no]-mX)*rX*g_ih[no]+b_ih[no] + (gs[no]-mH)*rH*g_hh[no]+b_hh[no];
    float co = c_src[(size_t)b*HID + n];
    float cn = sigm(gf)*co + sigm(gi)*tanh_f(gg);
    cN[rep]=cn; xo[rep]=go;
    sc += cn; sc2 += cn*cn;
  }
  #pragma unroll
  for (int m=32;m;m>>=1){ sc += __shfl_xor(sc,m); sc2 += __shfl_xor(sc2,m); }
  if ((tid&63)==0){ red[16+w]=sc; red[20+w]=sc2; }
  __syncthreads();
  sc  = red[16]+red[17]+red[18]+red[19];
  sc2 = red[20]+red[21]+red[22]+red[23];
  const float mC = sc*(1.f/HID);
  const float rC = rsqrtf(sc2*(1.f/HID)-mC*mC+EPSV);
  #pragma unroll
  for (int rep=0;rep<2;++rep){
    const int n = tid + rep*256;
    float hN = sigm(xo[rep])*tanh_f((cN[rep]-mC)*rC*g_c[n]+b_c[n]);
    c_dst[(size_t)b*HID+n] = cN[rep];
    unsigned short hbv = f2bf(hN);
    h_out[(size_t)b*HID+n] = hbv;
    lstm_out[((size_t)b*SEQ+t)*HID+n] = hbv;
  }
}

// ---------------- fused attention: scores -> softmax -> pooled -> scalar out ----------------
__global__ __launch_bounds__(256) void attn_out_k(
  const float* __restrict__ q, const unsigned short* __restrict__ Km,
  const unsigned short* __restrict__ lo_all,
  const float* __restrict__ u, const float* __restrict__ Cc,
  float* __restrict__ out)
{
  const int b = blockIdx.x, tid = threadIdx.x;
  __shared__ float qs[DK];
  __shared__ float sc[NH][SEQ];
  __shared__ float at[NH][SEQ];
  __shared__ float red[4];
  for (int i=tid; i<DK; i+=256) qs[i] = q[(size_t)b*DK + i];
  __syncthreads();
  {
    const int p = tid>>2, sub = tid&3, h = p>>4, s = p&15;
    const unsigned short* krow = Km + ((size_t)b*SEQ + s)*DK + h*DH + sub*32;
    const float* qh = &qs[h*DH + sub*32];
    float part = 0.f;
    #pragma unroll
    for (int c8=0;c8<4;++c8){
      u16x8 kv = *(const u16x8*)(krow + c8*8);
      #pragma unroll
      for (int j=0;j<8;++j) part += qh[c8*8+j]*bf2f(kv[j]);
    }
    part += __shfl_xor(part,1); part += __shfl_xor(part,2);
    if (sub==0) sc[h][s] = part * 0.08838834764831845f;
  }
  __syncthreads();
  if (tid < 64){
    const int h = tid>>4;
    float v = sc[h][tid&15], mx = v;
    #pragma unroll
    for (int m=1;m<16;m<<=1) mx = fmaxf(mx, __shfl_xor(mx,m));
    float e = __expf(v-mx), se = e;
    #pragma unroll
    for (int m=1;m<16;m<<=1) se += __shfl_xor(se,m);
    at[h][tid&15] = e/se;
  }
  __syncthreads();
  float accum = 0.f;
  #pragma unroll
  for (int it=0; it<4; ++it){
    const int idx = it*256 + tid;
    const int h = idx>>8, d0 = (idx&255)*2;
    const unsigned short* lo = lo_all + (size_t)b*SEQ*HID + d0;
    float p0=0.f, p1=0.f;
    #pragma unroll
    for (int s=0;s<16;++s){
      unsigned int pr = *(const unsigned int*)(lo + s*HID);
      float a = at[h][s];
      p0 += a*bf2f((unsigned short)(pr&0xffffu));
      p1 += a*bf2f((unsigned short)(pr>>16));
    }
    accum += u[h*HID+d0]*p0 + u[h*HID+d0+1]*p1;
  }
  #pragma unroll
  for (int m=32;m;m>>=1) accum += __shfl_xor(accum,m);
  if ((tid&63)==0) red[tid>>6] = accum;
  __syncthreads();
  if (tid==0) out[1+b] = red[0]+red[1]+red[2]+red[3] + Cc[0];
}

__global__ __launch_bounds__(256) void loss_k(const float* __restrict__ label, float* __restrict__ out){
  const int tid = threadIdx.x;
  __shared__ float red[4];
  float s = 0.f;
  for (int b=tid; b<B_SZ; b+=256){
    float d = out[1+b] - label[(size_t)b*SEQ + (SEQ-1)];
    s += d*d;
  }
  #pragma unroll
  for (int m=32;m;m>>=1) s += __shfl_xor(s,m);
  if ((tid&63)==0) red[tid>>6]=s;
  __syncthreads();
  if (tid==0) out[0] = (red[0]+red[1]+red[2]+red[3]) * (1.f/B_SZ);
}

__global__ __launch_bounds__(256) void cvt_bf16_k(const float* __restrict__ in, unsigned short* __restrict__ o, int n){
  int i = (blockIdx.x*256 + threadIdx.x)*4;
  if (i < n){
    f4_t v = *(const f4_t*)&in[i];
    u16x4 w;
    #pragma unroll
    for (int j=0;j<4;++j) w[j] = f2bf(v[j]);
    *(u16x4*)&o[i] = w;
  }
}

// -------- fold wout/out_W/wv into u[h,d] and scalar C (exact: sum(attn)==1) --------
__global__ __launch_bounds__(256) void fold_we_k(
  const float* __restrict__ wout_W, const float* __restrict__ out_W, float* __restrict__ we)
{
  const int j = blockIdx.x*256 + threadIdx.x;
  float s=0.f;
  for (int m=0;m<512;++m) s += out_W[m]*wout_W[(size_t)m*2048+j];
  we[j]=s;
}
__global__ __launch_bounds__(256) void fold_u_k(
  const float* __restrict__ we, const float* __restrict__ wv_W, float* __restrict__ u)
{
  const int o = blockIdx.x*256 + threadIdx.x;
  const int h = o>>9, d = o&511;
  const float* wv = wv_W + (size_t)h*262144 + d;
  const float* wp = we + h*512;
  float s=0.f;
  for (int k=0;k<512;++k) s += wp[k]*wv[(size_t)k*512];
  u[o]=s;
}
__global__ __launch_bounds__(256) void fold_c_k(
  const float* __restrict__ we, const float* __restrict__ wv_b,
  const float* __restrict__ out_W, const float* __restrict__ wout_b,
  const float* __restrict__ out_b, float* __restrict__ Cc)
{
  const int tid = threadIdx.x;
  __shared__ float red[4];
  float s=0.f;
  for (int j=tid;j<2048;j+=256) s += we[j]*wv_b[j];
  for (int m=tid;m<512;m+=256)  s += out_W[m]*wout_b[m];
  #pragma unroll
  for (int m=32;m;m>>=1) s += __shfl_xor(s,m);
  if ((tid&63)==0) red[tid>>6]=s;
  __syncthreads();
  if (tid==0) Cc[0] = red[0]+red[1]+red[2]+red[3] + out_b[0];
}

extern "C" void kernel_launch(void* const* d_in, const int* in_sizes, int n_in,
                              void* d_out, int out_size, void* d_ws, size_t ws_size,
                              hipStream_t stream)
{
  const float* visual = (const float*)d_in[0];
  const float* text   = (const float*)d_in[1];
  const float* user_  = (const float*)d_in[2];
  const float* cat_   = (const float*)d_in[3];
  const float* label  = (const float*)d_in[4];
  const float* h0     = (const float*)d_in[5];
  const float* c0     = (const float*)d_in[6];
  const float* fus_W  = (const float*)d_in[7];
  const float* fus_b  = (const float*)d_in[8];
  const float* W_ih   = (const float*)d_in[9];
  const float* W_hh   = (const float*)d_in[10];
  const float* g_ih   = (const float*)d_in[11];
  const float* b_ih   = (const float*)d_in[12];
  const float* g_hh   = (const float*)d_in[13];
  const float* b_hh   = (const float*)d_in[14];
  const float* g_c    = (const float*)d_in[15];
  const float* b_c    = (const float*)d_in[16];
  const float* wq_W   = (const float*)d_in[17];
  const float* wq_b   = (const float*)d_in[18];
  const float* wk_W   = (const float*)d_in[19];
  const float* wk_b   = (const float*)d_in[20];
  const float* wv_W   = (const float*)d_in[21];
  const float* wv_b   = (const float*)d_in[22];
  const float* wout_W = (const float*)d_in[23];
  const float* wout_b = (const float*)d_in[24];
  const float* out_W  = (const float*)d_in[25];
  const float* out_b  = (const float*)d_in[26];
  (void)in_sizes; (void)n_in; (void)out_size; (void)ws_size;

  char* base = (char*)d_ws; size_t off = 0;
  auto alloc = [&](size_t n)->void*{ void* p = base+off; off += n; off = (off+255)&~(size_t)255; return p; };
  unsigned short* X     = (unsigned short*)alloc((size_t)32768*2048*2);   // 128 MB
  unsigned short* vt    = (unsigned short*)alloc((size_t)32768*1024*2);   // 64 MB
  unsigned short* lo    = (unsigned short*)alloc((size_t)32768*512*2);    // 32 MB
  unsigned short* Km    = (unsigned short*)alloc((size_t)32768*512*2);    // 32 MB
  unsigned short* Gh    = (unsigned short*)alloc((size_t)2048*2048*2);    // 8 MB
  float*          cws   = (float*)         alloc((size_t)2048*512*4);     // 4 MB
  unsigned short* hb    = (unsigned short*)alloc((size_t)2048*512*2);
  float*          qb    = (float*)         alloc((size_t)2048*512*4);
  unsigned short* fusWb = (unsigned short*)alloc((size_t)1024*4096*2);
  unsigned short* Wihb  = (unsigned short*)alloc((size_t)2048*1024*2);
  unsigned short* Whhb  = (unsigned short*)alloc((size_t)2048*512*2);
  unsigned short* wqb   = (unsigned short*)alloc((size_t)512*512*2);
  unsigned short* wkb   = (unsigned short*)alloc((size_t)512*512*2);
  float*          we_ws = (float*)         alloc(2048*4);
  float*          u_ws  = (float*)         alloc(2048*4);
  float*          C_ws  = (float*)         alloc(256);

  // weight conversions + folds
  cvt_bf16_k<<<dim3(4096), dim3(256), 0, stream>>>(fus_W, fusWb, 1024*4096);
  cvt_bf16_k<<<dim3(2048), dim3(256), 0, stream>>>(W_ih,  Wihb,  2048*1024);
  cvt_bf16_k<<<dim3(1024), dim3(256), 0, stream>>>(W_hh,  Whhb,  2048*512);
  cvt_bf16_k<<<dim3(256),  dim3(256), 0, stream>>>(wq_W,  wqb,   512*512);
  cvt_bf16_k<<<dim3(256),  dim3(256), 0, stream>>>(wk_W,  wkb,   512*512);
  cvt_bf16_k<<<dim3(1024), dim3(256), 0, stream>>>(h0,    hb,    2048*512);
  fold_we_k<<<dim3(8), dim3(256), 0, stream>>>(wout_W, out_W, we_ws);
  fold_u_k <<<dim3(8), dim3(256), 0, stream>>>(we_ws, wv_W, u_ws);
  fold_c_k <<<dim3(1), dim3(256), 0, stream>>>(we_ws, wv_b, out_W, wout_b, out_b, C_ws);

  // GEMM1 (fused fp32-A cvt, 8-phase, quarter-pipelined): M=32768 N=1024 K=4096
  gemm8pf<<<dim3(512), dim3(512), 0, stream>>>(
      visual, text, user_, cat_, fusWb, fus_b, vt, 1024, 4096, 512);
  // GEMM2: X = vt @ W_ih^T  (bf16 out; LN renormalizes)  M=32768 N=2048 K=1024
  gemm8p<true,false,false><<<dim3(1024), dim3(512), 0, stream>>>(
      vt, Wihb, nullptr, X, 2048, 1024, 1024);

  // recurrence (r3-proven: 64x64 tiles -> 1024 WGs, 4/CU)
  for (int t=0; t<SEQ; ++t){
    gemm64<true,false><<<dim3(1024), dim3(256), 0, stream>>>(
        hb, Whhb, nullptr, Gh, 2048, 512, 1024);
    lstm_step<<<dim3(2048), dim3(256), 0, stream>>>(
        X, Gh, (t==0 ? c0 : cws), cws, g_ih, b_ih, g_hh, b_hh, g_c, b_c, hb, lo, t);
  }

  // q = hn @ wq_W^T + wq_b   (fp32 out)  M=2048 N=512 K=512
  gemm64<false,true><<<dim3(256), dim3(256), 0, stream>>>(
      hb, wqb, wq_b, qb, 512, 512, 256);
  // Kmat = lstm_out @ wk_W^T + wk_b  (bf16 out)  M=32768 N=512 K=512
  gemm8p<true,true,false><<<dim3(256), dim3(512), 0, stream>>>(
      lo, wkb, wk_b, Km, 512, 512, 256);

  attn_out_k<<<dim3(2048), dim3(256), 0, stream>>>(qb, Km, lo, u_ws, C_ws, (float*)d_out);
  loss_k<<<dim3(1), dim3(256), 0, stream>>>(label, (float*)d_out);
}

// Round 10
// 933.183 us; speedup vs baseline: 1.0761x; 1.0132x over previous
//
#include <hip/hip_runtime.h>
#include <cstdint>

#define B_SZ 2048
#define SEQ  16
#define DIM  1024
#define HID  512
#define DK   512
#define NH   4
#define DH   128
#define GATE 2048
#define EPSV 1e-5f

typedef __bf16 bf8_t __attribute__((ext_vector_type(8)));
typedef float  f4_t  __attribute__((ext_vector_type(4)));
typedef unsigned short u16x8 __attribute__((ext_vector_type(8)));
typedef unsigned short u16x4 __attribute__((ext_vector_type(4)));

__device__ __forceinline__ unsigned short f2bf(float f){
  __bf16 h = (__bf16)f;                       // RNE
  return __builtin_bit_cast(unsigned short, h);
}
__device__ __forceinline__ float bf2f(unsigned short u){
  return __builtin_bit_cast(float, ((unsigned int)u) << 16);
}
__device__ __forceinline__ float sigm(float x){ return 1.f/(1.f+__expf(-x)); }
__device__ __forceinline__ float tanh_f(float x){ return 1.f - 2.f/(__expf(2.f*x)+1.f); }

__device__ __forceinline__ void gload16(const void* g, void* l){
  __builtin_amdgcn_global_load_lds(
      (const __attribute__((address_space(1))) void*)g,
      (__attribute__((address_space(3))) void*)l, 16, 0, 0);
}

// ================= 256x256 8-phase pipelined BT GEMM, bf16 A (r7-proven 968 TF) =================
template<bool OUT_BF16, bool BIAS, bool RELU>
__global__ __launch_bounds__(512, 1) void gemm8p(
    const unsigned short* __restrict__ A,
    const unsigned short* __restrict__ Bw,
    const float* __restrict__ bias,
    void* __restrict__ Cp,
    int N, int K, int nwg)
{
  __shared__ __align__(16) unsigned short As[2][256*64];
  __shared__ __align__(16) unsigned short Bs[2][256*64];
  const int tid = threadIdx.x, lane = tid & 63, w = tid >> 6;
  const int bid = blockIdx.x;
  const int swz = (bid & 7)*(nwg >> 3) + (bid >> 3);   // nwg % 8 == 0 at all call sites
  const int nx  = N >> 8;
  const int lnx = 31 - __clz(nx);
  const int bm0 = (swz >> lnx) << 8;
  const int bn0 = (swz & (nx-1)) << 8;

  const int l8  = lane >> 3;
  const int gsw = (lane & 7) ^ l8;
  const int fr  = lane & 15, kg = lane >> 4;
  const int wm  = (w >> 2)*128, wn = (w & 3)*64;
  const int KT  = K >> 6;

  auto stA = [&](int buf, int kt, int h){
    #pragma unroll
    for (int c=0;c<2;++c){
      const int rb = h*128 + c*64 + w*8;
      gload16(A + (size_t)(bm0 + rb + l8)*K + (size_t)kt*64 + gsw*8, &As[buf][rb*64]);
    }
  };
  auto stB = [&](int buf, int kt, int h){
    #pragma unroll
    for (int c=0;c<2;++c){
      const int rb = h*128 + c*64 + w*8;
      gload16(Bw + (size_t)(bn0 + rb + l8)*K + (size_t)kt*64 + gsw*8, &Bs[buf][rb*64]);
    }
  };
  auto rdA = [&](int buf, int m, int kk)->bf8_t{
    return *(const bf8_t*)&As[buf][(wm + m*16 + fr)*64 + (((kk*4+kg) ^ (fr&7))*8)];
  };
  auto rdB = [&](int buf, int n, int kk)->bf8_t{
    return *(const bf8_t*)&Bs[buf][(wn + n*16 + fr)*64 + (((kk*4+kg) ^ (fr&7))*8)];
  };

  f4_t acc[8][4];
  #pragma unroll
  for (int m=0;m<8;++m)
    #pragma unroll
    for (int n=0;n<4;++n) acc[m][n] = (f4_t)0.f;

  bf8_t bfr[4][2];

  auto mfma2 = [&](int m0, const bf8_t a00, const bf8_t a01,
                   const bf8_t a10, const bf8_t a11){
    __builtin_amdgcn_s_setprio(1);
    #pragma unroll
    for (int n=0;n<4;++n){
      acc[m0][n]   = __builtin_amdgcn_mfma_f32_16x16x32_bf16(a00, bfr[n][0], acc[m0][n],   0,0,0);
      acc[m0][n]   = __builtin_amdgcn_mfma_f32_16x16x32_bf16(a01, bfr[n][1], acc[m0][n],   0,0,0);
      acc[m0+1][n] = __builtin_amdgcn_mfma_f32_16x16x32_bf16(a10, bfr[n][0], acc[m0+1][n], 0,0,0);
      acc[m0+1][n] = __builtin_amdgcn_mfma_f32_16x16x32_bf16(a11, bfr[n][1], acc[m0+1][n], 0,0,0);
    }
    __builtin_amdgcn_s_setprio(0);
  };

  auto phase12 = [&](int buf, auto&& stg){
    #pragma unroll
    for (int n=0;n<4;++n){ bfr[n][0]=rdB(buf,n,0); bfr[n][1]=rdB(buf,n,1); }
    const bf8_t a00=rdA(buf,0,0), a01=rdA(buf,0,1), a10=rdA(buf,1,0), a11=rdA(buf,1,1);
    stg();
    asm volatile("s_barrier" ::: "memory");
    mfma2(0, a00,a01,a10,a11);
    asm volatile("s_barrier" ::: "memory");
  };
  auto phase4 = [&](int buf, int m0, auto&& stg, bool vm){
    const bf8_t a00=rdA(buf,m0,0), a01=rdA(buf,m0,1), a10=rdA(buf,m0+1,0), a11=rdA(buf,m0+1,1);
    stg();
    if (vm){
      __builtin_amdgcn_sched_barrier(0);
      asm volatile("s_waitcnt vmcnt(4)" ::: "memory");
    }
    asm volatile("s_barrier" ::: "memory");
    mfma2(m0, a00,a01,a10,a11);
    asm volatile("s_barrier" ::: "memory");
  };

  stA(0,0,0); stA(0,0,1); stB(0,0,0); stB(0,0,1);
  stB(1,1,0); stB(1,1,1);
  __builtin_amdgcn_sched_barrier(0);
  asm volatile("s_waitcnt vmcnt(4)" ::: "memory");
  asm volatile("s_barrier" ::: "memory");

  const int NIT = KT >> 1;
  for (int it=0; it<NIT; ++it){
    const int t0 = 2*it, t1 = t0+1;
    const int tN  = (t0+2 < KT) ? t0+2 : KT-1;
    const int tB3 = (t1+2 < KT) ? t1+2 : KT-1;

    phase12(0,      [&]{ stA(1,t1,0);  });
    phase4 (0, 2,   [&]{ stA(1,t1,1);  }, false);
    phase4 (0, 4,   [&]{ stB(0,tN,0);  }, false);
    phase4 (0, 6,   [&]{ stB(0,tN,1);  }, true);
    phase12(1,      [&]{ stA(0,tN,0);  });
    phase4 (1, 2,   [&]{ stA(0,tN,1);  }, false);
    phase4 (1, 4,   [&]{ stB(1,tB3,0); }, false);
    phase4 (1, 6,   [&]{ stB(1,tB3,1); }, true);
  }

  #pragma unroll
  for (int n=0;n<4;++n){
    const int col = bn0 + wn + n*16 + fr;
    float bv = 0.f;
    if constexpr (BIAS) bv = bias[col];
    #pragma unroll
    for (int m=0;m<8;++m){
      #pragma unroll
      for (int j=0;j<4;++j){
        const int row = bm0 + wm + m*16 + kg*4 + j;
        float v = acc[m][n][j] + bv;
        if constexpr (RELU) v = fmaxf(v, 0.f);
        if constexpr (OUT_BF16) ((unsigned short*)Cp)[(size_t)row*N + col] = f2bf(v);
        else                    ((float*)Cp)[(size_t)row*N + col] = v;
      }
    }
  }
}

// ===== 256x256 8-phase GEMM, FUSED fp32->bf16 A, 4-deep quarter-pipelined staging (r10) =====
// A staged in 64-row quarters: 8 f32/thread, FOUR named reg sets rg0..rg3 (static idx, rule-20),
// ld issued 4 phases before its wr (~600+ cy lead vs HBM ~900).
// Schedule (iteration it; t1=2it+1, tN=t1+1, tB3=t1+2):
//   P0: wr1q0 ld0q0 | P1: wr1q1 ld0q1 | P2: wr1q2 stB(0,tN,0) ld0q2
//   P3: wr1q3 stB(0,tN,1) ld0q3 lgkm | P4: wr0q0 ld1q0(tB3) | P5: wr0q1 ld1q1
//   P6: wr0q2 stB(1,tB3,0) ld1q2 | P7: wr0q3 stB(1,tB3,1) ld1q3 lgkm
// LEDGER (in-order vmcnt forcing, m135; within-phase order wr < stB < [SB] < ld):
//   Bs[0](tN) staged P2/P3, read next-P0: P7's wr0q3 waits ld0q3@P3 (younger than
//     stB(0,tN,1)@P3) -> forces both halves before P7 trail barrier. ✓
//   Bs[1](tB3) staged P6/P7, read next-P4: next-iter P3's wr1q3 waits ld1q3@P7
//     (younger than stB(1,tB3,1)@P7) -> forced before that trail barrier. ✓
//   As[1](t1) wr P0..P3 (regs ld'd prev P4..P7) + lgkm@P3 -> resident for P4. ✓
//   As[0](tN) wr P4..P7 (regs ld'd P0..P3) + lgkm@P7 -> resident for next-P0. ✓
//   WAR: every buffer rewrite is after the trail barrier of its last-reading phase. ✓
//   Tail: tN/tB3 clamped to KT-1 (dead writes), counts stay uniform. ✓
__global__ __launch_bounds__(512, 1) void gemm8pf(
    const float* __restrict__ A0, const float* __restrict__ A1,
    const float* __restrict__ A2, const float* __restrict__ A3,
    const unsigned short* __restrict__ Bw,
    const float* __restrict__ bias,
    unsigned short* __restrict__ Cp,
    int N, int K, int nwg)
{
  __shared__ __align__(16) unsigned short As[2][256*64];
  __shared__ __align__(16) unsigned short Bs[2][256*64];
  const int tid = threadIdx.x, lane = tid & 63, w = tid >> 6;
  const int bid = blockIdx.x;
  const int swz = (bid & 7)*(nwg >> 3) + (bid >> 3);
  const int nx  = N >> 8;
  const int lnx = 31 - __clz(nx);
  const int bm0 = (swz >> lnx) << 8;
  const int bn0 = (swz & (nx-1)) << 8;

  const int l8  = lane >> 3;
  const int gsw = (lane & 7) ^ l8;
  const int fr  = lane & 15, kg = lane >> 4;
  const int wm  = (w >> 2)*128, wn = (w & 3)*64;
  const int KT  = K >> 6;

  auto stB = [&](int buf, int kt, int h){
    #pragma unroll
    for (int c=0;c<2;++c){
      const int rb = h*128 + c*64 + w*8;
      gload16(Bw + (size_t)(bn0 + rb + l8)*K + (size_t)kt*64 + gsw*8, &Bs[buf][rb*64]);
    }
  };

  // quarter staging: row = q*64 + tid>>3 (64 rows/q), 8 f32 at chunk tid&7
  f4_t rg0[2], rg1[2], rg2[2], rg3[2];
  auto ldQ = [&](f4_t* rg, int kt, int q){
    const int kb = kt*64, si = kb >> 10, kc = kb & 1023;
    const float* Asel = si==0?A0 : si==1?A1 : si==2?A2 : A3;
    const float* p = Asel + (size_t)(bm0 + q*64 + (tid>>3))*1024 + kc + (tid&7)*8;
    rg[0] = *(const f4_t*)p; rg[1] = *(const f4_t*)(p+4);
  };
  auto wrQ = [&](const f4_t* rg, int buf, int q){
    const int R = q*64 + (tid>>3);
    const int g = (tid&7) ^ (R&7);          // same involution as rdA
    u16x8 wv;
    #pragma unroll
    for (int j=0;j<4;++j){ wv[j]=f2bf(rg[0][j]); wv[4+j]=f2bf(rg[1][j]); }
    *(u16x8*)&As[buf][R*64 + g*8] = wv;
  };

  auto rdA = [&](int buf, int m, int kk)->bf8_t{
    return *(const bf8_t*)&As[buf][(wm + m*16 + fr)*64 + (((kk*4+kg) ^ (fr&7))*8)];
  };
  auto rdB = [&](int buf, int n, int kk)->bf8_t{
    return *(const bf8_t*)&Bs[buf][(wn + n*16 + fr)*64 + (((kk*4+kg) ^ (fr&7))*8)];
  };

  f4_t acc[8][4];
  #pragma unroll
  for (int m=0;m<8;++m)
    #pragma unroll
    for (int n=0;n<4;++n) acc[m][n] = (f4_t)0.f;

  bf8_t bfr[4][2];

  auto mfma2 = [&](int m0, const bf8_t a00, const bf8_t a01,
                   const bf8_t a10, const bf8_t a11){
    __builtin_amdgcn_s_setprio(1);
    #pragma unroll
    for (int n=0;n<4;++n){
      acc[m0][n]   = __builtin_amdgcn_mfma_f32_16x16x32_bf16(a00, bfr[n][0], acc[m0][n],   0,0,0);
      acc[m0][n]   = __builtin_amdgcn_mfma_f32_16x16x32_bf16(a01, bfr[n][1], acc[m0][n],   0,0,0);
      acc[m0+1][n] = __builtin_amdgcn_mfma_f32_16x16x32_bf16(a10, bfr[n][0], acc[m0+1][n], 0,0,0);
      acc[m0+1][n] = __builtin_amdgcn_mfma_f32_16x16x32_bf16(a11, bfr[n][1], acc[m0+1][n], 0,0,0);
    }
    __builtin_amdgcn_s_setprio(0);
  };

  auto phase12 = [&](int buf, auto&& stg){
    #pragma unroll
    for (int n=0;n<4;++n){ bfr[n][0]=rdB(buf,n,0); bfr[n][1]=rdB(buf,n,1); }
    const bf8_t a00=rdA(buf,0,0), a01=rdA(buf,0,1), a10=rdA(buf,1,0), a11=rdA(buf,1,1);
    stg();
    asm volatile("s_barrier" ::: "memory");
    mfma2(0, a00,a01,a10,a11);
    asm volatile("s_barrier" ::: "memory");
  };
  auto phase4 = [&](int buf, int m0, auto&& stg){
    const bf8_t a00=rdA(buf,m0,0), a01=rdA(buf,m0,1), a10=rdA(buf,m0+1,0), a11=rdA(buf,m0+1,1);
    stg();
    asm volatile("s_barrier" ::: "memory");
    mfma2(m0, a00,a01,a10,a11);
    asm volatile("s_barrier" ::: "memory");
  };

  // prologue: stage B(0)/B(1); A(0) serial ld+wr (auto-waits force stB complete);
  // prime tile-1 quarters into all 4 sets (in flight across the barrier).
  stB(0,0,0); stB(0,0,1); stB(1,1,0); stB(1,1,1);
  ldQ(rg0,0,0); ldQ(rg1,0,1); ldQ(rg2,0,2); ldQ(rg3,0,3);
  wrQ(rg0,0,0); wrQ(rg1,0,1); wrQ(rg2,0,2); wrQ(rg3,0,3);
  __builtin_amdgcn_sched_barrier(0);
  ldQ(rg0,1,0); ldQ(rg1,1,1); ldQ(rg2,1,2); ldQ(rg3,1,3);
  asm volatile("s_waitcnt lgkmcnt(0)" ::: "memory");
  asm volatile("s_barrier" ::: "memory");

  const int NIT = KT >> 1;
  for (int it=0; it<NIT; ++it){
    const int t1  = 2*it+1;
    const int tN  = (t1+1 < KT) ? t1+1 : KT-1;   // clamped: dead writes on last iter
    const int tB3 = (t1+2 < KT) ? t1+2 : KT-1;

    // P0: wr1q0 (ld@prev P4), ld0q0(tN)
    phase12(0, [&]{ wrQ(rg0,1,0); __builtin_amdgcn_sched_barrier(0); ldQ(rg0,tN,0); });
    // P1: wr1q1, ld0q1
    phase4 (0, 2, [&]{ wrQ(rg1,1,1); __builtin_amdgcn_sched_barrier(0); ldQ(rg1,tN,1); });
    // P2: wr1q2, stB(0,tN,0), ld0q2   [ld pinned after stB]
    phase4 (0, 4, [&]{ wrQ(rg2,1,2); stB(0,tN,0);
                       __builtin_amdgcn_sched_barrier(0); ldQ(rg2,tN,2); });
    // P3: wr1q3, stB(0,tN,1), ld0q3, lgkm
    phase4 (0, 6, [&]{ wrQ(rg3,1,3); stB(0,tN,1);
                       __builtin_amdgcn_sched_barrier(0); ldQ(rg3,tN,3);
                       __builtin_amdgcn_sched_barrier(0);
                       asm volatile("s_waitcnt lgkmcnt(0)":::"memory"); });
    // P4: wr0q0 (ld@P0), ld1q0(tB3)
    phase12(1, [&]{ wrQ(rg0,0,0); __builtin_amdgcn_sched_barrier(0); ldQ(rg0,tB3,0); });
    // P5: wr0q1, ld1q1
    phase4 (1, 2, [&]{ wrQ(rg1,0,1); __builtin_amdgcn_sched_barrier(0); ldQ(rg1,tB3,1); });
    // P6: wr0q2, stB(1,tB3,0), ld1q2
    phase4 (1, 4, [&]{ wrQ(rg2,0,2); stB(1,tB3,0);
                       __builtin_amdgcn_sched_barrier(0); ldQ(rg2,tB3,2); });
    // P7: wr0q3, stB(1,tB3,1), ld1q3, lgkm
    phase4 (1, 6, [&]{ wrQ(rg3,0,3); stB(1,tB3,1);
                       __builtin_amdgcn_sched_barrier(0); ldQ(rg3,tB3,3);
                       __builtin_amdgcn_sched_barrier(0);
                       asm volatile("s_waitcnt lgkmcnt(0)":::"memory"); });
  }

  #pragma unroll
  for (int n=0;n<4;++n){
    const int col = bn0 + wn + n*16 + fr;
    const float bv = bias[col];
    #pragma unroll
    for (int m=0;m<8;++m){
      #pragma unroll
      for (int j=0;j<4;++j){
        const int row = bm0 + wm + m*16 + kg*4 + j;
        float v = fmaxf(acc[m][n][j] + bv, 0.f);
        Cp[(size_t)row*N + col] = f2bf(v);
      }
    }
  }
}

// ------------- bf16 BT GEMM 64x64 (high-occupancy, small recurrent GEMMs; r3-proven) -------------
template<bool OUT_BF16, bool BIAS>
__global__ __launch_bounds__(256) void gemm64(
    const unsigned short* __restrict__ A,
    const unsigned short* __restrict__ Bw,
    const float* __restrict__ bias,
    void* __restrict__ Cp,
    int N, int K, int nwg)
{
  __shared__ __align__(16) unsigned short As[64*64];
  __shared__ __align__(16) unsigned short Bs[64*64];
  const int tid = threadIdx.x, lane = tid & 63, wave = tid >> 6;
  const int bid = blockIdx.x;
  const int swz = (bid & 7)*(nwg >> 3) + (bid >> 3);
  const int nx  = N >> 6;
  const int lnx = 31 - __clz(nx);
  const int bm0 = (swz >> lnx) << 6;
  const int bn0 = (swz & (nx-1)) << 6;

  const int r8  = lane >> 3;
  const int gsw = ((lane & 7) ^ r8) * 8;
  const unsigned short* Ab = A  + (size_t)(bm0 + wave*16 + r8)*K + gsw;
  const unsigned short* Bb = Bw + (size_t)(bn0 + wave*16 + r8)*K + gsw;
  unsigned short* la = As + wave*1024;
  unsigned short* lb = Bs + wave*1024;

  f4_t acc[2][2];
  #pragma unroll
  for (int m=0;m<2;++m)
    #pragma unroll
    for (int n=0;n<2;++n) acc[m][n] = (f4_t)0.f;

  const int KT = K >> 6;
  const int fr = lane & 15, kg = lane >> 4;
  const int wm = (wave & 1)*32, wn = (wave >> 1)*32;

  for (int kt = 0; kt < KT; ++kt){
    if (kt) __syncthreads();
    const size_t ko = (size_t)kt*64;
    #pragma unroll
    for (int q = 0; q < 2; ++q){
      gload16(Ab + ko + (size_t)q*8*K, la + q*512);
      gload16(Bb + ko + (size_t)q*8*K, lb + q*512);
    }
    __syncthreads();
    #pragma unroll
    for (int kk = 0; kk < 2; ++kk){
      bf8_t af[2], bf_[2];
      #pragma unroll
      for (int m=0;m<2;++m){
        const int r = wm+m*16+fr;
        af[m]  = *(const bf8_t*)&As[r*64 + (((kk*4+kg) ^ (r&7))*8)];
      }
      #pragma unroll
      for (int n=0;n<2;++n){
        const int r = wn+n*16+fr;
        bf_[n] = *(const bf8_t*)&Bs[r*64 + (((kk*4+kg) ^ (r&7))*8)];
      }
      #pragma unroll
      for (int m=0;m<2;++m)
        #pragma unroll
        for (int n=0;n<2;++n)
          acc[m][n] = __builtin_amdgcn_mfma_f32_16x16x32_bf16(af[m], bf_[n], acc[m][n], 0,0,0);
    }
  }

  #pragma unroll
  for (int n=0;n<2;++n){
    const int col = bn0 + wn + n*16 + fr;
    float bv = 0.f;
    if constexpr (BIAS) bv = bias[col];
    #pragma unroll
    for (int m=0;m<2;++m){
      #pragma unroll
      for (int j=0;j<4;++j){
        const int row = bm0 + wm + m*16 + kg*4 + j;
        float v = acc[m][n][j] + bv;
        if constexpr (OUT_BF16) ((unsigned short*)Cp)[(size_t)row*N + col] = f2bf(v);
        else                    ((float*)Cp)[(size_t)row*N + col] = v;
      }
    }
  }
}

// ---------------- fused LN + LSTM elementwise step (one WG per batch row; r3-proven) ----------------
__global__ __launch_bounds__(256) void lstm_step(
  const unsigned short* __restrict__ X, const unsigned short* __restrict__ Gh,
  const float* __restrict__ c_src, float* __restrict__ c_dst,
  const float* __restrict__ g_ih, const float* __restrict__ b_ih,
  const float* __restrict__ g_hh, const float* __restrict__ b_hh,
  const float* __restrict__ g_c,  const float* __restrict__ b_c,
  unsigned short* __restrict__ h_out, unsigned short* __restrict__ lstm_out,
  int t)
{
  const int b = blockIdx.x, tid = threadIdx.x;
  __shared__ float xs[GATE];
  __shared__ float gs[GATE];
  __shared__ float red[32];
  const unsigned short* xrow = X  + ((size_t)b*SEQ + t)*GATE;
  const unsigned short* grow = Gh + (size_t)b*GATE;
  u16x8 xv = *(const u16x8*)&xrow[tid*8];
  u16x8 gv = *(const u16x8*)&grow[tid*8];
  float sx=0,sx2=0,sg=0,sg2=0;
  #pragma unroll
  for (int j=0;j<8;++j){
    float x = bf2f(xv[j]), g = bf2f(gv[j]);
    xs[tid*8+j]=x; gs[tid*8+j]=g;
    sx += x; sx2 += x*x; sg += g; sg2 += g*g;
  }
  #pragma unroll
  for (int m=32;m;m>>=1){
    sx += __shfl_xor(sx,m); sx2 += __shfl_xor(sx2,m);
    sg += __shfl_xor(sg,m); sg2 += __shfl_xor(sg2,m);
  }
  const int w = tid>>6;
  if ((tid&63)==0){ red[w]=sx; red[4+w]=sx2; red[8+w]=sg; red[12+w]=sg2; }
  __syncthreads();
  sx  = red[0]+red[1]+red[2]+red[3];
  sx2 = red[4]+red[5]+red[6]+red[7];
  sg  = red[8]+red[9]+red[10]+red[11];
  sg2 = red[12]+red[13]+red[14]+red[15];
  const float mX = sx*(1.f/GATE), mH = sg*(1.f/GATE);
  const float rX = rsqrtf(sx2*(1.f/GATE)-mX*mX+EPSV);
  const float rH = rsqrtf(sg2*(1.f/GATE)-mH*mH+EPSV);

  float cN[2], xo[2]; float sc=0, sc2=0;
  #pragma unroll
  for (int rep=0;rep<2;++rep){
    const int n = tid + rep*256;
    const int ni=n, nf=n+HID, ng=n+2*HID, no=n+3*HID;
    float gi = (xs[ni]-mX)*rX*g_ih[ni]+b_ih[ni] + (gs[ni]-mH)*rH*g_hh[ni]+b_hh[ni];
    float gf = (xs[nf]-mX)*rX*g_ih[nf]+b_ih[nf] + (gs[nf]-mH)*rH*g_hh[nf]+b_hh[nf];
    float gg = (xs[ng]-mX)*rX*g_ih[ng]+b_ih[ng] + (gs[ng]-mH)*rH*g_hh[ng]+b_hh[ng];
    float go = (xs[no]-mX)*rX*g_ih[no]+b_ih[no] + (gs[no]-mH)*rH*g_hh[no]+b_hh[no];
    float co = c_src[(size_t)b*HID + n];
    float cn = sigm(gf)*co + sigm(gi)*tanh_f(gg);
    cN[rep]=cn; xo[rep]=go;
    sc += cn; sc2 += cn*cn;
  }
  #pragma unroll
  for (int m=32;m;m>>=1){ sc += __shfl_xor(sc,m); sc2 += __shfl_xor(sc2,m); }
  if ((tid&63)==0){ red[16+w]=sc; red[20+w]=sc2; }
  __syncthreads();
  sc  = red[16]+red[17]+red[18]+red[19];
  sc2 = red[20]+red[21]+red[22]+red[23];
  const float mC = sc*(1.f/HID);
  const float rC = rsqrtf(sc2*(1.f/HID)-mC*mC+EPSV);
  #pragma unroll
  for (int rep=0;rep<2;++rep){
    const int n = tid + rep*256;
    float hN = sigm(xo[rep])*tanh_f((cN[rep]-mC)*rC*g_c[n]+b_c[n]);
    c_dst[(size_t)b*HID+n] = cN[rep];
    unsigned short hbv = f2bf(hN);
    h_out[(size_t)b*HID+n] = hbv;
    lstm_out[((size_t)b*SEQ+t)*HID+n] = hbv;
  }
}

// ---------------- fused attention: scores -> softmax -> pooled -> scalar out ----------------
__global__ __launch_bounds__(256) void attn_out_k(
  const float* __restrict__ q, const unsigned short* __restrict__ Km,
  const unsigned short* __restrict__ lo_all,
  const float* __restrict__ u, const float* __restrict__ Cc,
  float* __restrict__ out)
{
  const int b = blockIdx.x, tid = threadIdx.x;
  __shared__ float qs[DK];
  __shared__ float sc[NH][SEQ];
  __shared__ float at[NH][SEQ];
  __shared__ float red[4];
  for (int i=tid; i<DK; i+=256) qs[i] = q[(size_t)b*DK + i];
  __syncthreads();
  {
    const int p = tid>>2, sub = tid&3, h = p>>4, s = p&15;
    const unsigned short* krow = Km + ((size_t)b*SEQ + s)*DK + h*DH + sub*32;
    const float* qh = &qs[h*DH + sub*32];
    float part = 0.f;
    #pragma unroll
    for (int c8=0;c8<4;++c8){
      u16x8 kv = *(const u16x8*)(krow + c8*8);
      #pragma unroll
      for (int j=0;j<8;++j) part += qh[c8*8+j]*bf2f(kv[j]);
    }
    part += __shfl_xor(part,1); part += __shfl_xor(part,2);
    if (sub==0) sc[h][s] = part * 0.08838834764831845f;
  }
  __syncthreads();
  if (tid < 64){
    const int h = tid>>4;
    float v = sc[h][tid&15], mx = v;
    #pragma unroll
    for (int m=1;m<16;m<<=1) mx = fmaxf(mx, __shfl_xor(mx,m));
    float e = __expf(v-mx), se = e;
    #pragma unroll
    for (int m=1;m<16;m<<=1) se += __shfl_xor(se,m);
    at[h][tid&15] = e/se;
  }
  __syncthreads();
  float accum = 0.f;
  #pragma unroll
  for (int it=0; it<4; ++it){
    const int idx = it*256 + tid;
    const int h = idx>>8, d0 = (idx&255)*2;
    const unsigned short* lo = lo_all + (size_t)b*SEQ*HID + d0;
    float p0=0.f, p1=0.f;
    #pragma unroll
    for (int s=0;s<16;++s){
      unsigned int pr = *(const unsigned int*)(lo + s*HID);
      float a = at[h][s];
      p0 += a*bf2f((unsigned short)(pr&0xffffu));
      p1 += a*bf2f((unsigned short)(pr>>16));
    }
    accum += u[h*HID+d0]*p0 + u[h*HID+d0+1]*p1;
  }
  #pragma unroll
  for (int m=32;m;m>>=1) accum += __shfl_xor(accum,m);
  if ((tid&63)==0) red[tid>>6] = accum;
  __syncthreads();
  if (tid==0) out[1+b] = red[0]+red[1]+red[2]+red[3] + Cc[0];
}

__global__ __launch_bounds__(256) void loss_k(const float* __restrict__ label, float* __restrict__ out){
  const int tid = threadIdx.x;
  __shared__ float red[4];
  float s = 0.f;
  for (int b=tid; b<B_SZ; b+=256){
    float d = out[1+b] - label[(size_t)b*SEQ + (SEQ-1)];
    s += d*d;
  }
  #pragma unroll
  for (int m=32;m;m>>=1) s += __shfl_xor(s,m);
  if ((tid&63)==0) red[tid>>6]=s;
  __syncthreads();
  if (tid==0) out[0] = (red[0]+red[1]+red[2]+red[3]) * (1.f/B_SZ);
}

__global__ __launch_bounds__(256) void cvt_bf16_k(const float* __restrict__ in, unsigned short* __restrict__ o, int n){
  int i = (blockIdx.x*256 + threadIdx.x)*4;
  if (i < n){
    f4_t v = *(const f4_t*)&in[i];
    u16x4 w;
    #pragma unroll
    for (int j=0;j<4;++j) w[j] = f2bf(v[j]);
    *(u16x4*)&o[i] = w;
  }
}

// -------- fold wout/out_W/wv into u[h,d] and scalar C (exact: sum(attn)==1) --------
__global__ __launch_bounds__(256) void fold_we_k(
  const float* __restrict__ wout_W, const float* __restrict__ out_W, float* __restrict__ we)
{
  const int j = blockIdx.x*256 + threadIdx.x;
  float s=0.f;
  for (int m=0;m<512;++m) s += out_W[m]*wout_W[(size_t)m*2048+j];
  we[j]=s;
}
__global__ __launch_bounds__(256) void fold_u_k(
  const float* __restrict__ we, const float* __restrict__ wv_W, float* __restrict__ u)
{
  const int o = blockIdx.x*256 + threadIdx.x;
  const int h = o>>9, d = o&511;
  const float* wv = wv_W + (size_t)h*262144 + d;
  const float* wp = we + h*512;
  float s=0.f;
  for (int k=0;k<512;++k) s += wp[k]*wv[(size_t)k*512];
  u[o]=s;
}
__global__ __launch_bounds__(256) void fold_c_k(
  const float* __restrict__ we, const float* __restrict__ wv_b,
  const float* __restrict__ out_W, const float* __restrict__ wout_b,
  const float* __restrict__ out_b, float* __restrict__ Cc)
{
  const int tid = threadIdx.x;
  __shared__ float red[4];
  float s=0.f;
  for (int j=tid;j<2048;j+=256) s += we[j]*wv_b[j];
  for (int m=tid;m<512;m+=256)  s += out_W[m]*wout_b[m];
  #pragma unroll
  for (int m=32;m;m>>=1) s += __shfl_xor(s,m);
  if ((tid&63)==0) red[tid>>6]=s;
  __syncthreads();
  if (tid==0) Cc[0] = red[0]+red[1]+red[2]+red[3] + out_b[0];
}

extern "C" void kernel_launch(void* const* d_in, const int* in_sizes, int n_in,
                              void* d_out, int out_size, void* d_ws, size_t ws_size,
                              hipStream_t stream)
{
  const float* visual = (const float*)d_in[0];
  const float* text   = (const float*)d_in[1];
  const float* user_  = (const float*)d_in[2];
  const float* cat_   = (const float*)d_in[3];
  const float* label  = (const float*)d_in[4];
  const float* h0     = (const float*)d_in[5];
  const float* c0     = (const float*)d_in[6];
  const float* fus_W  = (const float*)d_in[7];
  const float* fus_b  = (const float*)d_in[8];
  const float* W_ih   = (const float*)d_in[9];
  const float* W_hh   = (const float*)d_in[10];
  const float* g_ih   = (const float*)d_in[11];
  const float* b_ih   = (const float*)d_in[12];
  const float* g_hh   = (const float*)d_in[13];
  const float* b_hh   = (const float*)d_in[14];
  const float* g_c    = (const float*)d_in[15];
  const float* b_c    = (const float*)d_in[16];
  const float* wq_W   = (const float*)d_in[17];
  const float* wq_b   = (const float*)d_in[18];
  const float* wk_W   = (const float*)d_in[19];
  const float* wk_b   = (const float*)d_in[20];
  const float* wv_W   = (const float*)d_in[21];
  const float* wv_b   = (const float*)d_in[22];
  const float* wout_W = (const float*)d_in[23];
  const float* wout_b = (const float*)d_in[24];
  const float* out_W  = (const float*)d_in[25];
  const float* out_b  = (const float*)d_in[26];
  (void)in_sizes; (void)n_in; (void)out_size; (void)ws_size;

  char* base = (char*)d_ws; size_t off = 0;
  auto alloc = [&](size_t n)->void*{ void* p = base+off; off += n; off = (off+255)&~(size_t)255; return p; };
  unsigned short* X     = (unsigned short*)alloc((size_t)32768*2048*2);   // 128 MB
  unsigned short* vt    = (unsigned short*)alloc((size_t)32768*1024*2);   // 64 MB
  unsigned short* lo    = (unsigned short*)alloc((size_t)32768*512*2);    // 32 MB
  unsigned short* Km    = (unsigned short*)alloc((size_t)32768*512*2);    // 32 MB
  unsigned short* Gh    = (unsigned short*)alloc((size_t)2048*2048*2);    // 8 MB
  float*          cws   = (float*)         alloc((size_t)2048*512*4);     // 4 MB
  unsigned short* hb    = (unsigned short*)alloc((size_t)2048*512*2);
  float*          qb    = (float*)         alloc((size_t)2048*512*4);
  unsigned short* fusWb = (unsigned short*)alloc((size_t)1024*4096*2);
  unsigned short* Wihb  = (unsigned short*)alloc((size_t)2048*1024*2);
  unsigned short* Whhb  = (unsigned short*)alloc((size_t)2048*512*2);
  unsigned short* wqb   = (unsigned short*)alloc((size_t)512*512*2);
  unsigned short* wkb   = (unsigned short*)alloc((size_t)512*512*2);
  float*          we_ws = (float*)         alloc(2048*4);
  float*          u_ws  = (float*)         alloc(2048*4);
  float*          C_ws  = (float*)         alloc(256);

  // weight conversions + folds
  cvt_bf16_k<<<dim3(4096), dim3(256), 0, stream>>>(fus_W, fusWb, 1024*4096);
  cvt_bf16_k<<<dim3(2048), dim3(256), 0, stream>>>(W_ih,  Wihb,  2048*1024);
  cvt_bf16_k<<<dim3(1024), dim3(256), 0, stream>>>(W_hh,  Whhb,  2048*512);
  cvt_bf16_k<<<dim3(256),  dim3(256), 0, stream>>>(wq_W,  wqb,   512*512);
  cvt_bf16_k<<<dim3(256),  dim3(256), 0, stream>>>(wk_W,  wkb,   512*512);
  cvt_bf16_k<<<dim3(1024), dim3(256), 0, stream>>>(h0,    hb,    2048*512);
  fold_we_k<<<dim3(8), dim3(256), 0, stream>>>(wout_W, out_W, we_ws);
  fold_u_k <<<dim3(8), dim3(256), 0, stream>>>(we_ws, wv_W, u_ws);
  fold_c_k <<<dim3(1), dim3(256), 0, stream>>>(we_ws, wv_b, out_W, wout_b, out_b, C_ws);

  // GEMM1 (fused fp32-A cvt, 8-phase, 4-deep quarter pipeline): M=32768 N=1024 K=4096
  gemm8pf<<<dim3(512), dim3(512), 0, stream>>>(
      visual, text, user_, cat_, fusWb, fus_b, vt, 1024, 4096, 512);
  // GEMM2: X = vt @ W_ih^T  (bf16 out; LN renormalizes)  M=32768 N=2048 K=1024
  gemm8p<true,false,false><<<dim3(1024), dim3(512), 0, stream>>>(
      vt, Wihb, nullptr, X, 2048, 1024, 1024);

  // recurrence (r3-proven: 64x64 tiles -> 1024 WGs, 4/CU)
  for (int t=0; t<SEQ; ++t){
    gemm64<true,false><<<dim3(1024), dim3(256), 0, stream>>>(
        hb, Whhb, nullptr, Gh, 2048, 512, 1024);
    lstm_step<<<dim3(2048), dim3(256), 0, stream>>>(
        X, Gh, (t==0 ? c0 : cws), cws, g_ih, b_ih, g_hh, b_hh, g_c, b_c, hb, lo, t);
  }

  // q = hn @ wq_W^T + wq_b   (fp32 out)  M=2048 N=512 K=512
  gemm64<false,true><<<dim3(256), dim3(256), 0, stream>>>(
      hb, wqb, wq_b, qb, 512, 512, 256);
  // Kmat = lstm_out @ wk_W^T + wk_b  (bf16 out)  M=32768 N=512 K=512
  gemm8p<true,true,false><<<dim3(256), dim3(512), 0, stream>>>(
      lo, wkb, wk_b, Km, 512, 512, 256);

  attn_out_k<<<dim3(2048), dim3(256), 0, stream>>>(qb, Km, lo, u_ws, C_ws, (float*)d_out);
  loss_k<<<dim3(1), dim3(256), 0, stream>>>(label, (float*)d_out);
}